// Round 8
// baseline (634.562 us; speedup 1.0000x reference)
//
#include <hip/hip_runtime.h>

#define EMB 600
#define Q4  150   // EMB / 4
#define KP  608   // K padded (19 * 32)

typedef unsigned short ushortT;
typedef __attribute__((ext_vector_type(8))) short short8;
typedef __attribute__((ext_vector_type(4))) short short4v;
typedef __attribute__((ext_vector_type(4))) float f32x4;

__device__ __forceinline__ float4 f4add(float4 a, float4 b) {
    return make_float4(a.x + b.x, a.y + b.y, a.z + b.z, a.w + b.w);
}
__device__ __forceinline__ float4 f4fma(float4 acc, float4 v, float4 e) {
    return make_float4(fmaf(v.x, e.x, acc.x), fmaf(v.y, e.y, acc.y),
                       fmaf(v.z, e.z, acc.z), fmaf(v.w, e.w, acc.w));
}
__device__ __forceinline__ ushortT bf16_rne(float x) {
    unsigned u = __float_as_uint(x);
    return (ushortT)((u + 0x7fffu + ((u >> 16) & 1u)) >> 16);
}
__device__ __forceinline__ float bf16_to_f(ushortT h) {
    return __uint_as_float(((unsigned)h) << 16);
}

// fragment-interleaved offset (ushort units) for element (row, col):
// tile = (row/16)*19 + col/32, lane slot = (row&15) + 16*((col>>3)&3),
// within-short8 = col&7.
__device__ __forceinline__ size_t frag_off(int row, int col) {
    return ((size_t)((row >> 4) * 19 + (col >> 5)) * 64
            + (row & 15) + 16 * ((col >> 3) & 3)) * 8 + (col & 7);
}

// ---------------------------------------------------------------------------
// K1: node embedding = sum of 5 table lookups.
// ---------------------------------------------------------------------------
__global__ void k_node_embed(const int* __restrict__ atom,
                             const float4* __restrict__ Wa,
                             const float4* __restrict__ Wh,
                             const float4* __restrict__ War,
                             const float4* __restrict__ Wc,
                             const float4* __restrict__ Wch,
                             float4* __restrict__ out, int N) {
    int idx = blockIdx.x * blockDim.x + threadIdx.x;
    int total = N * Q4;
    if (idx >= total) return;
    int n = idx / Q4;
    int q = idx - n * Q4;
    const int* a = atom + n * 5;
    float4 r = Wa[a[0] * Q4 + q];
    r = f4add(r, Wh [a[1] * Q4 + q]);
    r = f4add(r, War[a[2] * Q4 + q]);
    r = f4add(r, Wc [a[3] * Q4 + q]);
    r = f4add(r, Wch[a[4] * Q4 + q]);
    out[idx] = r;
}

// ---------------------------------------------------------------------------
// CSR build: histogram -> scan -> scatter
// ---------------------------------------------------------------------------
__global__ void k_hist(const int* __restrict__ bdst, int* __restrict__ counts, int E) {
    int i = blockIdx.x * blockDim.x + threadIdx.x;
    if (i < E) atomicAdd(&counts[bdst[i]], 1);
}

__global__ __launch_bounds__(1024) void k_scan(const int* __restrict__ counts,
                                               int* __restrict__ offsets,
                                               int* __restrict__ cursor, int N) {
    __shared__ int sums[1024];
    int t = threadIdx.x;
    int chunk = (N + 1023) / 1024;
    int begin = t * chunk;
    int end = begin + chunk; if (end > N) end = N;
    int s = 0;
    for (int i = begin; i < end; i++) s += counts[i];
    sums[t] = s;
    __syncthreads();
    for (int off = 1; off < 1024; off <<= 1) {
        int v = (t >= off) ? sums[t - off] : 0;
        __syncthreads();
        sums[t] += v;
        __syncthreads();
    }
    int run = (t == 0) ? 0 : sums[t - 1];
    for (int i = begin; i < end; i++) {
        offsets[i] = run;
        cursor[i]  = run;
        run += counts[i];
    }
}

__global__ void k_scatter(const int* __restrict__ bdst, int* __restrict__ cursor,
                          int* __restrict__ edge_list, int E) {
    int i = blockIdx.x * blockDim.x + threadIdx.x;
    if (i < E) {
        int pos = atomicAdd(&cursor[bdst[i]], 1);
        edge_list[pos] = i;
    }
}

// ---------------------------------------------------------------------------
// K2a: MP round 1 (fp32 out). One wave per dest node. Edge-meta prefetch.
// ---------------------------------------------------------------------------
__global__ __launch_bounds__(256) void k_mp_gather(
        const int* __restrict__ bsrc, const int* __restrict__ battr,
        const int* __restrict__ atom,
        const int* __restrict__ offsets, const int* __restrict__ counts,
        const int* __restrict__ edge_list,
        const float4* __restrict__ Wbt, const float4* __restrict__ Wbai,
        const float4* __restrict__ Wsla, const float4* __restrict__ Wsl,
        const float4* __restrict__ in, float4* __restrict__ out, int N) {
    int wid  = (int)((blockIdx.x * blockDim.x + threadIdx.x) >> 6);
    int lane = threadIdx.x & 63;
    if (wid >= N) return;
    int d = wid;
    int q0 = lane, q1 = lane + 64, q2 = lane + 128;
    bool has2 = (q2 < Q4);

    int start = offsets[d], cnt = counts[d];
    int s = 0, t0 = 0, t1 = 0;
    if (cnt > 0) {
        int eid = edge_list[start];
        s  = bsrc[eid];
        t0 = battr[eid * 2 + 0];
        t1 = battr[eid * 2 + 1];
    }

    const float4* slA = Wsla + atom[d * 5] * Q4;
    const float4* inr = in + (size_t)d * Q4;
    float4 acc0 = make_float4(0, 0, 0, 0), acc1 = acc0, acc2 = acc0;
    acc0 = f4fma(acc0, inr[q0], f4add(slA[q0], Wsl[q0]));
    acc1 = f4fma(acc1, inr[q1], f4add(slA[q1], Wsl[q1]));
    if (has2) acc2 = f4fma(acc2, inr[q2], f4add(slA[q2], Wsl[q2]));

    for (int k = 0; k < cnt; k++) {
        int ns = s, nt0 = t0, nt1 = t1;
        if (k + 1 < cnt) {
            int ne = edge_list[start + k + 1];
            ns  = bsrc[ne];
            nt0 = battr[ne * 2 + 0];
            nt1 = battr[ne * 2 + 1];
        }
        const float4* e0 = Wbt  + t0 * Q4;
        const float4* e1 = Wbai + t1 * Q4;
        const float4* sr = in + (size_t)s * Q4;
        acc0 = f4fma(acc0, sr[q0], f4add(e0[q0], e1[q0]));
        acc1 = f4fma(acc1, sr[q1], f4add(e0[q1], e1[q1]));
        if (has2) acc2 = f4fma(acc2, sr[q2], f4add(e0[q2], e1[q2]));
        s = ns; t0 = nt0; t1 = nt1;
    }
    float4* orow = out + (size_t)d * Q4;
    orow[q0] = acc0;
    orow[q1] = acc1;
    if (has2) orow[q2] = acc2;
}

// ---------------------------------------------------------------------------
// K2b: MP round 2 fused with relu + bf16 hi/lo split, written directly in
// FRAGMENT-INTERLEAVED layout (A-operand of GEMM1). q-chunk q covers
// k = 4q..4q+3 -> kc = q>>3, ks = (q>>1)&3, half = q&1.
// ---------------------------------------------------------------------------
__device__ __forceinline__ void frag_store4(ushortT* __restrict__ hi,
                                            ushortT* __restrict__ lo,
                                            int d, int q, float4 v) {
    int kc = q >> 3, ks = (q >> 1) & 3, half = q & 1;
    size_t off = ((size_t)((d >> 4) * 19 + kc) * 64 + (d & 15) + 16 * ks) * 8
                 + half * 4;
    float vv[4] = {v.x, v.y, v.z, v.w};
    short4v h4, l4;
#pragma unroll
    for (int j = 0; j < 4; j++) {
        float x = fmaxf(vv[j], 0.f);
        ushortT hh = bf16_rne(x);
        h4[j] = (short)hh;
        l4[j] = (short)bf16_rne(x - bf16_to_f(hh));
    }
    *(short4v*)(hi + off) = h4;
    *(short4v*)(lo + off) = l4;
}

__global__ __launch_bounds__(256) void k_mp_gather_rs(
        const int* __restrict__ bsrc, const int* __restrict__ battr,
        const int* __restrict__ atom,
        const int* __restrict__ offsets, const int* __restrict__ counts,
        const int* __restrict__ edge_list,
        const float4* __restrict__ Wbt, const float4* __restrict__ Wbai,
        const float4* __restrict__ Wsla, const float4* __restrict__ Wsl,
        const float4* __restrict__ in,
        ushortT* __restrict__ hi, ushortT* __restrict__ lo, int N) {
    int wid  = (int)((blockIdx.x * blockDim.x + threadIdx.x) >> 6);
    int lane = threadIdx.x & 63;
    if (wid >= N) return;
    int d = wid;
    int q0 = lane, q1 = lane + 64, q2 = lane + 128;
    bool has2 = (q2 < Q4);

    int start = offsets[d], cnt = counts[d];
    int s = 0, t0 = 0, t1 = 0;
    if (cnt > 0) {
        int eid = edge_list[start];
        s  = bsrc[eid];
        t0 = battr[eid * 2 + 0];
        t1 = battr[eid * 2 + 1];
    }

    const float4* slA = Wsla + atom[d * 5] * Q4;
    const float4* inr = in + (size_t)d * Q4;
    float4 acc0 = make_float4(0, 0, 0, 0), acc1 = acc0, acc2 = acc0;
    acc0 = f4fma(acc0, inr[q0], f4add(slA[q0], Wsl[q0]));
    acc1 = f4fma(acc1, inr[q1], f4add(slA[q1], Wsl[q1]));
    if (has2) acc2 = f4fma(acc2, inr[q2], f4add(slA[q2], Wsl[q2]));

    for (int k = 0; k < cnt; k++) {
        int ns = s, nt0 = t0, nt1 = t1;
        if (k + 1 < cnt) {
            int ne = edge_list[start + k + 1];
            ns  = bsrc[ne];
            nt0 = battr[ne * 2 + 0];
            nt1 = battr[ne * 2 + 1];
        }
        const float4* e0 = Wbt  + t0 * Q4;
        const float4* e1 = Wbai + t1 * Q4;
        const float4* sr = in + (size_t)s * Q4;
        acc0 = f4fma(acc0, sr[q0], f4add(e0[q0], e1[q0]));
        acc1 = f4fma(acc1, sr[q1], f4add(e0[q1], e1[q1]));
        if (has2) acc2 = f4fma(acc2, sr[q2], f4add(e0[q2], e1[q2]));
        s = ns; t0 = nt0; t1 = nt1;
    }
    frag_store4(hi, lo, d, q0, acc0);
    frag_store4(hi, lo, d, q1, acc1);
    if (has2) frag_store4(hi, lo, d, q2, acc2);
    if (lane == 31) {   // zero K-pad cols 600..607 (kc=18, ks=3 slot)
        size_t off = ((size_t)((d >> 4) * 19 + 18) * 64 + (d & 15) + 48) * 8;
        short8 z = {0, 0, 0, 0, 0, 0, 0, 0};
        *(short8*)(hi + off) = z;
        *(short8*)(lo + off) = z;
    }
}

// ---------------------------------------------------------------------------
// Weight split to FRAGMENT-INTERLEAVED layout: tile (cb, kc) = 1 KB, lane l
// holds W[col=cb*16+(l&15)][k8=(l>>4)] as short8. hi/lo bf16 split.
// ---------------------------------------------------------------------------
__global__ void k_split_w_frag(const float* __restrict__ src,
                               short8* __restrict__ dhi, short8* __restrict__ dlo,
                               int rows_in, int cb_count) {
    int idx = blockIdx.x * blockDim.x + threadIdx.x;
    int total = cb_count * 19 * 64;
    if (idx >= total) return;
    int lane = idx & 63;
    int tile = idx >> 6;
    int cb = tile / 19, kc = tile - cb * 19;
    int col = cb * 16 + (lane & 15);
    int k0  = kc * 32 + (lane >> 4) * 8;
    short8 h, l;
#pragma unroll
    for (int j = 0; j < 8; j++) {
        int k = k0 + j;
        float x = (col < rows_in && k < 600) ? src[(size_t)col * 600 + k] : 0.f;
        ushortT hh = bf16_rne(x);
        h[j] = (short)hh;
        l[j] = (short)bf16_rne(x - bf16_to_f(hh));
    }
    dhi[idx] = h;
    dlo[idx] = l;
}

// ---------------------------------------------------------------------------
// Register GEMM core (bf16x3): 128x128 block tile, 4 independent waves each
// owning a 64x64 quadrant. NO LDS, NO barriers: both operands are read
// straight global->VGPR from fragment-interleaved layout (L2-hot), double
// buffered over kc. Cross-wave hazards structurally impossible.
// ---------------------------------------------------------------------------
struct FragSet { short8 ah[4], al[4], bh[4], bl[4]; };

__device__ __forceinline__ void frag_load(FragSet& f,
        const short8* __restrict__ Afh, const short8* __restrict__ Afl,
        const short8* __restrict__ Bfh, const short8* __restrict__ Bfl,
        int aBase, int bBase, int kc) {
    int ak = aBase + kc * 64;
    int bk = bBase + kc * 64;
#pragma unroll
    for (int i = 0; i < 4; i++) {
        f.ah[i] = Afh[ak + i * 1216];   // 1216 = 19*64 short8 per row-block
        f.al[i] = Afl[ak + i * 1216];
        f.bh[i] = Bfh[bk + i * 1216];
        f.bl[i] = Bfl[bk + i * 1216];
    }
}

__device__ __forceinline__ void frag_mfma(const FragSet& f, f32x4 acc[4][4]) {
#pragma unroll
    for (int i = 0; i < 4; i++)
#pragma unroll
        for (int j = 0; j < 4; j++) {
            acc[i][j] = __builtin_amdgcn_mfma_f32_16x16x32_bf16(f.ah[i], f.bh[j], acc[i][j], 0, 0, 0);
            acc[i][j] = __builtin_amdgcn_mfma_f32_16x16x32_bf16(f.ah[i], f.bl[j], acc[i][j], 0, 0, 0);
            acc[i][j] = __builtin_amdgcn_mfma_f32_16x16x32_bf16(f.al[i], f.bh[j], acc[i][j], 0, 0, 0);
        }
}

__device__ __forceinline__ void gemm_core_reg(
        const short8* __restrict__ Afh, const short8* __restrict__ Afl,
        const short8* __restrict__ Bfh, const short8* __restrict__ Bfl,
        int aBase, int bBase, f32x4 acc[4][4]) {
    FragSet f0, f1;
    frag_load(f0, Afh, Afl, Bfh, Bfl, aBase, bBase, 0);
    for (int k2 = 0; k2 < 9; k2++) {
        frag_load(f1, Afh, Afl, Bfh, Bfl, aBase, bBase, 2 * k2 + 1);
        frag_mfma(f0, acc);
        frag_load(f0, Afh, Afl, Bfh, Bfl, aBase, bBase, 2 * k2 + 2);
        frag_mfma(f1, acc);
    }
    frag_mfma(f0, acc);   // kc = 18
}

// m204 bijective XCD swizzle
__device__ __forceinline__ void decode_wg(int ncb, int& rowblk, int& colblk) {
    int nwg  = gridDim.x;
    int orig = blockIdx.x;
    int q = nwg >> 3, r = nwg & 7;
    int xcd = orig & 7, rank = orig >> 3;
    int wgid = (xcd < r ? xcd * (q + 1) : r * (q + 1) + (xcd - r) * q) + rank;
    rowblk = wgid / ncb;
    colblk = wgid - rowblk * ncb;
}

// GEMM1: H = relu(A @ W1^T + b1) -> Hf (fragment-interleaved). grid Mb*5.
__global__ __launch_bounds__(256) void k_gemm1r(
        const short8* __restrict__ Afh, const short8* __restrict__ Afl,
        const short8* __restrict__ Wfh, const short8* __restrict__ Wfl,
        const float* __restrict__ b1,
        ushortT* __restrict__ Hfh, ushortT* __restrict__ Hfl, int N) {
    int rowblk, colblk;
    decode_wg(5, rowblk, colblk);
    int row0 = rowblk * 128;
    int col0 = colblk * 128;
    int t = threadIdx.x, w = t >> 6, l = t & 63;
    int wr = w >> 1, wc = w & 1, fr = l & 15, fq = l >> 4;

    int aBase = (rowblk * 8 + wr * 4) * 1216 + l;
    int bBase = (colblk * 8 + wc * 4) * 1216 + l;
    f32x4 acc[4][4];
#pragma unroll
    for (int i = 0; i < 4; i++)
#pragma unroll
        for (int j = 0; j < 4; j++) acc[i][j] = f32x4{0.f, 0.f, 0.f, 0.f};
    gemm_core_reg(Afh, Afl, Wfh, Wfl, aBase, bBase, acc);

#pragma unroll
    for (int i = 0; i < 4; i++) {
#pragma unroll
        for (int j = 0; j < 4; j++) {
            int col = col0 + wc * 64 + j * 16 + fr;
            float bias = (col < 600) ? b1[col] : 0.f;
#pragma unroll
            for (int r = 0; r < 4; r++) {
                int row = row0 + wr * 64 + i * 16 + fq * 4 + r;
                if (row >= N) continue;
                if (col < 600) {
                    float x = fmaxf(acc[i][j][r] + bias, 0.f);
                    ushortT hh = bf16_rne(x);
                    size_t off = frag_off(row, col);
                    Hfh[off] = hh;
                    Hfl[off] = bf16_rne(x - bf16_to_f(hh));
                } else if (col < KP) {
                    size_t off = frag_off(row, col);
                    Hfh[off] = 0;
                    Hfl[off] = 0;
                }
            }
        }
    }
}

// GEMM2: energy += sum_col relu(H @ W2^T + b2) * W3. grid Mb*3.
__global__ __launch_bounds__(256) void k_gemm2r(
        const short8* __restrict__ Afh, const short8* __restrict__ Afl,
        const short8* __restrict__ Wfh, const short8* __restrict__ Wfl,
        const float* __restrict__ b2, const float* __restrict__ W3,
        float* __restrict__ energy, int N) {
    __shared__ float sE[128];
    int rowblk, colblk;
    decode_wg(3, rowblk, colblk);
    int row0 = rowblk * 128;
    int col0 = colblk * 128;
    int t = threadIdx.x, w = t >> 6, l = t & 63;
    int wr = w >> 1, wc = w & 1, fr = l & 15, fq = l >> 4;

    int aBase = (rowblk * 8 + wr * 4) * 1216 + l;
    int bBase = (colblk * 8 + wc * 4) * 1216 + l;
    f32x4 acc[4][4];
#pragma unroll
    for (int i = 0; i < 4; i++)
#pragma unroll
        for (int j = 0; j < 4; j++) acc[i][j] = f32x4{0.f, 0.f, 0.f, 0.f};
    gemm_core_reg(Afh, Afl, Wfh, Wfl, aBase, bBase, acc);

    if (t < 128) sE[t] = 0.f;
    __syncthreads();
#pragma unroll
    for (int i = 0; i < 4; i++) {
        float p[4] = {0.f, 0.f, 0.f, 0.f};
#pragma unroll
        for (int j = 0; j < 4; j++) {
            int col = col0 + wc * 64 + j * 16 + fr;
            if (col < 300) {
                float bias = b2[col];
                float wv   = W3[col];
#pragma unroll
                for (int r = 0; r < 4; r++)
                    p[r] += fmaxf(acc[i][j][r] + bias, 0.f) * wv;
            }
        }
#pragma unroll
        for (int r = 0; r < 4; r++) {
            float v = p[r];
            v += __shfl_xor(v, 1, 64);
            v += __shfl_xor(v, 2, 64);
            v += __shfl_xor(v, 4, 64);
            v += __shfl_xor(v, 8, 64);
            p[r] = v;
        }
        if (fr == 0) {
#pragma unroll
            for (int r = 0; r < 4; r++)
                atomicAdd(&sE[wr * 64 + i * 16 + fq * 4 + r], p[r]);
        }
    }
    __syncthreads();
    if (t < 128) {
        int row = row0 + t;
        if (row < N) atomicAdd(&energy[row], sE[t]);
    }
}

// ---------------------------------------------------------------------------
// K5: per-graph pool. batch sorted -> wave-segmented reduce, few atomics.
// ---------------------------------------------------------------------------
__global__ void k_pool(const float* __restrict__ energy, const int* __restrict__ batch,
                       float* __restrict__ dg, int N) {
    int i = blockIdx.x * blockDim.x + threadIdx.x;
    int lane = threadIdx.x & 63;
    float v = (i < N) ? energy[i] : 0.f;
    int   b = (i < N) ? batch[i]  : -1;
#pragma unroll
    for (int off = 1; off < 64; off <<= 1) {
        float vv = __shfl_down(v, off, 64);
        int   bb = __shfl_down(b, off, 64);
        if (lane + off < 64 && bb == b) v += vv;
    }
    int pb = __shfl_up(b, 1, 64);
    if (i < N && (lane == 0 || pb != b)) atomicAdd(&dg[b], v);
}

extern "C" void kernel_launch(void* const* d_in, const int* in_sizes, int n_in,
                              void* d_out, int out_size, void* d_ws, size_t ws_size,
                              hipStream_t stream) {
    const int* atom       = (const int*)d_in[0];
    const int* bond_index = (const int*)d_in[1];
    const int* bond_attr  = (const int*)d_in[2];
    const int* batch      = (const int*)d_in[3];
    const float* Wa   = (const float*)d_in[4];
    const float* Wh   = (const float*)d_in[5];
    const float* War  = (const float*)d_in[6];
    const float* Wc   = (const float*)d_in[7];
    const float* Wch  = (const float*)d_in[8];
    const float* Wbt  = (const float*)d_in[9];
    const float* Wbai = (const float*)d_in[10];
    const float* Wsla = (const float*)d_in[11];
    const float* Wsl  = (const float*)d_in[12];
    const float* W1   = (const float*)d_in[13];
    const float* b1   = (const float*)d_in[14];
    const float* W2   = (const float*)d_in[15];
    const float* b2   = (const float*)d_in[16];
    const float* W3   = (const float*)d_in[17];

    int N = in_sizes[0] / 5;   // 50000
    int E = in_sizes[1] / 2;   // 100000
    int Mb = (N + 127) / 128;  // 391
    int Npad = Mb * 128;       // 50048
    int nTiles = Npad / 16;    // 3128 row-blocks

    size_t regionBytes = (size_t)Npad * KP * 4;
    char* base = (char*)d_ws;
    float* nodeA = (float*)base;                       // region0: embed out, mp1 in
    float* nodeB = (float*)(base + regionBytes);       // region1: mp1 out, mp2 in
    // region0 reused as A-frags (mp2 out, gemm1 in); region1 as H-frags
    short8* Afh = (short8*)nodeA;
    short8* Afl = Afh + (size_t)nTiles * 1216;
    short8* Hfh = (short8*)nodeB;
    short8* Hfl = Hfh + (size_t)nTiles * 1216;
    char* tail = base + 2 * regionBytes;
    float* energy  = (float*)tail;
    int* counts    = (int*)(energy + N);
    int* offsets   = counts + N;
    int* cursor    = offsets + N;
    int* edge_list = cursor + N;
    short8* W1fh   = (short8*)(edge_list + E);         // 40*19*64 tiles
    short8* W1fl   = W1fh + 40 * 19 * 64;
    short8* W2fh   = W1fl + 40 * 19 * 64;              // 24*19*64 tiles
    short8* W2fl   = W2fh + 24 * 19 * 64;

    const int* bsrc = bond_index;
    const int* bdst = bond_index + E;

    // CSR build (dst -> edges)
    hipMemsetAsync(counts, 0, (size_t)N * sizeof(int), stream);
    k_hist<<<(E + 255) / 256, 256, 0, stream>>>(bdst, counts, E);
    k_scan<<<1, 1024, 0, stream>>>(counts, offsets, cursor, N);
    k_scatter<<<(E + 255) / 256, 256, 0, stream>>>(bdst, cursor, edge_list, E);

    // weight splits to fragment-interleaved layout
    k_split_w_frag<<<(40 * 19 * 64 + 255) / 256, 256, 0, stream>>>(W1, W1fh, W1fl, 600, 40);
    k_split_w_frag<<<(24 * 19 * 64 + 255) / 256, 256, 0, stream>>>(W2, W2fh, W2fl, 300, 24);

    // K1: node embedding -> nodeA
    {
        int total = N * Q4;
        k_node_embed<<<(total + 255) / 256, 256, 0, stream>>>(
            atom, (const float4*)Wa, (const float4*)Wh, (const float4*)War,
            (const float4*)Wc, (const float4*)Wch, (float4*)nodeA, N);
    }

    int mpblocks = (N * 64 + 255) / 256;
    // round 1: nodeA -> nodeB (fp32)
    k_mp_gather<<<mpblocks, 256, 0, stream>>>(bsrc, bond_attr, atom,
        offsets, counts, edge_list,
        (const float4*)Wbt, (const float4*)Wbai, (const float4*)Wsla, (const float4*)Wsl,
        (const float4*)nodeA, (float4*)nodeB, N);

    // zero A-frag pad tiles (rows N..Npad; region0 is dead fp32 now)
    {
        int firstPad = N / 16;                  // boundary tile memset then overwritten
        size_t offB  = (size_t)firstPad * 1216 * 16;   // bytes into each piece
        size_t cntB  = (size_t)(nTiles - firstPad) * 1216 * 16;
        if (cntB) {
            hipMemsetAsync((char*)Afh + offB, 0, cntB, stream);
            hipMemsetAsync((char*)Afl + offB, 0, cntB, stream);
        }
    }

    // round 2 fused with relu+split into fragment layout: nodeB -> Afh/Afl
    k_mp_gather_rs<<<mpblocks, 256, 0, stream>>>(bsrc, bond_attr, atom,
        offsets, counts, edge_list,
        (const float4*)Wbt, (const float4*)Wbai, (const float4*)Wsla, (const float4*)Wsl,
        (const float4*)nodeB, (ushortT*)Afh, (ushortT*)Afl, N);

    // GEMM1: Af x W1f -> Hf (region1; nodeB dead)
    k_gemm1r<<<Mb * 5, 256, 0, stream>>>(Afh, Afl, W1fh, W1fl, b1,
                                         (ushortT*)Hfh, (ushortT*)Hfl, N);

    // GEMM2: Hf x W2f (+b2, W3) -> energy (atomic accumulate)
    hipMemsetAsync(energy, 0, (size_t)N * sizeof(float), stream);
    k_gemm2r<<<Mb * 3, 256, 0, stream>>>(Hfh, Hfl, W2fh, W2fl, b2, W3, energy, N);

    // pool
    hipMemsetAsync(d_out, 0, (size_t)out_size * sizeof(float), stream);
    k_pool<<<(N + 255) / 256, 256, 0, stream>>>(energy, batch, (float*)d_out, N);
}

// Round 9
// 584.564 us; speedup vs baseline: 1.0855x; 1.0855x over previous
//
#include <hip/hip_runtime.h>

#define EMB 600
#define Q4  150   // EMB / 4
#define KP  608   // K padded (19 * 32)

typedef unsigned short ushortT;
typedef __attribute__((ext_vector_type(8))) short short8;
typedef __attribute__((ext_vector_type(4))) short short4v;
typedef __attribute__((ext_vector_type(4))) float f32x4;

__device__ __forceinline__ float4 f4add(float4 a, float4 b) {
    return make_float4(a.x + b.x, a.y + b.y, a.z + b.z, a.w + b.w);
}
__device__ __forceinline__ float4 f4fma(float4 acc, float4 v, float4 e) {
    return make_float4(fmaf(v.x, e.x, acc.x), fmaf(v.y, e.y, acc.y),
                       fmaf(v.z, e.z, acc.z), fmaf(v.w, e.w, acc.w));
}
__device__ __forceinline__ ushortT bf16_rne(float x) {
    unsigned u = __float_as_uint(x);
    return (ushortT)((u + 0x7fffu + ((u >> 16) & 1u)) >> 16);
}
__device__ __forceinline__ float bf16_to_f(ushortT h) {
    return __uint_as_float(((unsigned)h) << 16);
}

// fragment-interleaved offset (ushort units) for element (row, col)
__device__ __forceinline__ size_t frag_off(int row, int col) {
    return ((size_t)((row >> 4) * 19 + (col >> 5)) * 64
            + (row & 15) + 16 * ((col >> 3) & 3)) * 8 + (col & 7);
}

// ---------------------------------------------------------------------------
// K1: node embedding = sum of 5 table lookups.
// ---------------------------------------------------------------------------
__global__ void k_node_embed(const int* __restrict__ atom,
                             const float4* __restrict__ Wa,
                             const float4* __restrict__ Wh,
                             const float4* __restrict__ War,
                             const float4* __restrict__ Wc,
                             const float4* __restrict__ Wch,
                             float4* __restrict__ out, int N) {
    int idx = blockIdx.x * blockDim.x + threadIdx.x;
    int total = N * Q4;
    if (idx >= total) return;
    int n = idx / Q4;
    int q = idx - n * Q4;
    const int* a = atom + n * 5;
    float4 r = Wa[a[0] * Q4 + q];
    r = f4add(r, Wh [a[1] * Q4 + q]);
    r = f4add(r, War[a[2] * Q4 + q]);
    r = f4add(r, Wc [a[3] * Q4 + q]);
    r = f4add(r, Wch[a[4] * Q4 + q]);
    out[idx] = r;
}

// ---------------------------------------------------------------------------
// CSR build: histogram -> scan -> scatter
// ---------------------------------------------------------------------------
__global__ void k_hist(const int* __restrict__ bdst, int* __restrict__ counts, int E) {
    int i = blockIdx.x * blockDim.x + threadIdx.x;
    if (i < E) atomicAdd(&counts[bdst[i]], 1);
}

__global__ __launch_bounds__(1024) void k_scan(const int* __restrict__ counts,
                                               int* __restrict__ offsets,
                                               int* __restrict__ cursor, int N) {
    __shared__ int sums[1024];
    int t = threadIdx.x;
    int chunk = (N + 1023) / 1024;
    int begin = t * chunk;
    int end = begin + chunk; if (end > N) end = N;
    int s = 0;
    for (int i = begin; i < end; i++) s += counts[i];
    sums[t] = s;
    __syncthreads();
    for (int off = 1; off < 1024; off <<= 1) {
        int v = (t >= off) ? sums[t - off] : 0;
        __syncthreads();
        sums[t] += v;
        __syncthreads();
    }
    int run = (t == 0) ? 0 : sums[t - 1];
    for (int i = begin; i < end; i++) {
        offsets[i] = run;
        cursor[i]  = run;
        run += counts[i];
    }
}

__global__ void k_scatter(const int* __restrict__ bdst, int* __restrict__ cursor,
                          int* __restrict__ edge_list, int E) {
    int i = blockIdx.x * blockDim.x + threadIdx.x;
    if (i < E) {
        int pos = atomicAdd(&cursor[bdst[i]], 1);
        edge_list[pos] = i;
    }
}

// ---------------------------------------------------------------------------
// K2a: MP round 1 (fp32 out). One wave per dest node. Edge-meta prefetch.
// ---------------------------------------------------------------------------
__global__ __launch_bounds__(256) void k_mp_gather(
        const int* __restrict__ bsrc, const int* __restrict__ battr,
        const int* __restrict__ atom,
        const int* __restrict__ offsets, const int* __restrict__ counts,
        const int* __restrict__ edge_list,
        const float4* __restrict__ Wbt, const float4* __restrict__ Wbai,
        const float4* __restrict__ Wsla, const float4* __restrict__ Wsl,
        const float4* __restrict__ in, float4* __restrict__ out, int N) {
    int wid  = (int)((blockIdx.x * blockDim.x + threadIdx.x) >> 6);
    int lane = threadIdx.x & 63;
    if (wid >= N) return;
    int d = wid;
    int q0 = lane, q1 = lane + 64, q2 = lane + 128;
    bool has2 = (q2 < Q4);

    int start = offsets[d], cnt = counts[d];
    int s = 0, t0 = 0, t1 = 0;
    if (cnt > 0) {
        int eid = edge_list[start];
        s  = bsrc[eid];
        t0 = battr[eid * 2 + 0];
        t1 = battr[eid * 2 + 1];
    }

    const float4* slA = Wsla + atom[d * 5] * Q4;
    const float4* inr = in + (size_t)d * Q4;
    float4 acc0 = make_float4(0, 0, 0, 0), acc1 = acc0, acc2 = acc0;
    acc0 = f4fma(acc0, inr[q0], f4add(slA[q0], Wsl[q0]));
    acc1 = f4fma(acc1, inr[q1], f4add(slA[q1], Wsl[q1]));
    if (has2) acc2 = f4fma(acc2, inr[q2], f4add(slA[q2], Wsl[q2]));

    for (int k = 0; k < cnt; k++) {
        int ns = s, nt0 = t0, nt1 = t1;
        if (k + 1 < cnt) {
            int ne = edge_list[start + k + 1];
            ns  = bsrc[ne];
            nt0 = battr[ne * 2 + 0];
            nt1 = battr[ne * 2 + 1];
        }
        const float4* e0 = Wbt  + t0 * Q4;
        const float4* e1 = Wbai + t1 * Q4;
        const float4* sr = in + (size_t)s * Q4;
        acc0 = f4fma(acc0, sr[q0], f4add(e0[q0], e1[q0]));
        acc1 = f4fma(acc1, sr[q1], f4add(e0[q1], e1[q1]));
        if (has2) acc2 = f4fma(acc2, sr[q2], f4add(e0[q2], e1[q2]));
        s = ns; t0 = nt0; t1 = nt1;
    }
    float4* orow = out + (size_t)d * Q4;
    orow[q0] = acc0;
    orow[q1] = acc1;
    if (has2) orow[q2] = acc2;
}

// ---------------------------------------------------------------------------
// K2b: MP round 2 fused with relu + bf16 hi/lo split, fragment-interleaved out.
// ---------------------------------------------------------------------------
__device__ __forceinline__ void frag_store4(ushortT* __restrict__ hi,
                                            ushortT* __restrict__ lo,
                                            int d, int q, float4 v) {
    int kc = q >> 3, ks = (q >> 1) & 3, half = q & 1;
    size_t off = ((size_t)((d >> 4) * 19 + kc) * 64 + (d & 15) + 16 * ks) * 8
                 + half * 4;
    float vv[4] = {v.x, v.y, v.z, v.w};
    short4v h4, l4;
#pragma unroll
    for (int j = 0; j < 4; j++) {
        float x = fmaxf(vv[j], 0.f);
        ushortT hh = bf16_rne(x);
        h4[j] = (short)hh;
        l4[j] = (short)bf16_rne(x - bf16_to_f(hh));
    }
    *(short4v*)(hi + off) = h4;
    *(short4v*)(lo + off) = l4;
}

__global__ __launch_bounds__(256) void k_mp_gather_rs(
        const int* __restrict__ bsrc, const int* __restrict__ battr,
        const int* __restrict__ atom,
        const int* __restrict__ offsets, const int* __restrict__ counts,
        const int* __restrict__ edge_list,
        const float4* __restrict__ Wbt, const float4* __restrict__ Wbai,
        const float4* __restrict__ Wsla, const float4* __restrict__ Wsl,
        const float4* __restrict__ in,
        ushortT* __restrict__ hi, ushortT* __restrict__ lo, int N) {
    int wid  = (int)((blockIdx.x * blockDim.x + threadIdx.x) >> 6);
    int lane = threadIdx.x & 63;
    if (wid >= N) return;
    int d = wid;
    int q0 = lane, q1 = lane + 64, q2 = lane + 128;
    bool has2 = (q2 < Q4);

    int start = offsets[d], cnt = counts[d];
    int s = 0, t0 = 0, t1 = 0;
    if (cnt > 0) {
        int eid = edge_list[start];
        s  = bsrc[eid];
        t0 = battr[eid * 2 + 0];
        t1 = battr[eid * 2 + 1];
    }

    const float4* slA = Wsla + atom[d * 5] * Q4;
    const float4* inr = in + (size_t)d * Q4;
    float4 acc0 = make_float4(0, 0, 0, 0), acc1 = acc0, acc2 = acc0;
    acc0 = f4fma(acc0, inr[q0], f4add(slA[q0], Wsl[q0]));
    acc1 = f4fma(acc1, inr[q1], f4add(slA[q1], Wsl[q1]));
    if (has2) acc2 = f4fma(acc2, inr[q2], f4add(slA[q2], Wsl[q2]));

    for (int k = 0; k < cnt; k++) {
        int ns = s, nt0 = t0, nt1 = t1;
        if (k + 1 < cnt) {
            int ne = edge_list[start + k + 1];
            ns  = bsrc[ne];
            nt0 = battr[ne * 2 + 0];
            nt1 = battr[ne * 2 + 1];
        }
        const float4* e0 = Wbt  + t0 * Q4;
        const float4* e1 = Wbai + t1 * Q4;
        const float4* sr = in + (size_t)s * Q4;
        acc0 = f4fma(acc0, sr[q0], f4add(e0[q0], e1[q0]));
        acc1 = f4fma(acc1, sr[q1], f4add(e0[q1], e1[q1]));
        if (has2) acc2 = f4fma(acc2, sr[q2], f4add(e0[q2], e1[q2]));
        s = ns; t0 = nt0; t1 = nt1;
    }
    frag_store4(hi, lo, d, q0, acc0);
    frag_store4(hi, lo, d, q1, acc1);
    if (has2) frag_store4(hi, lo, d, q2, acc2);
    if (lane == 31) {   // zero K-pad cols 600..607 (kc=18, ks=3 slot)
        size_t off = ((size_t)((d >> 4) * 19 + 18) * 64 + (d & 15) + 48) * 8;
        short8 z = {0, 0, 0, 0, 0, 0, 0, 0};
        *(short8*)(hi + off) = z;
        *(short8*)(lo + off) = z;
    }
}

// ---------------------------------------------------------------------------
// Weight split to FRAGMENT-INTERLEAVED layout.
// ---------------------------------------------------------------------------
__global__ void k_split_w_frag(const float* __restrict__ src,
                               short8* __restrict__ dhi, short8* __restrict__ dlo,
                               int rows_in, int cb_count) {
    int idx = blockIdx.x * blockDim.x + threadIdx.x;
    int total = cb_count * 19 * 64;
    if (idx >= total) return;
    int lane = idx & 63;
    int tile = idx >> 6;
    int cb = tile / 19, kc = tile - cb * 19;
    int col = cb * 16 + (lane & 15);
    int k0  = kc * 32 + (lane >> 4) * 8;
    short8 h, l;
#pragma unroll
    for (int j = 0; j < 8; j++) {
        int k = k0 + j;
        float x = (col < rows_in && k < 600) ? src[(size_t)col * 600 + k] : 0.f;
        ushortT hh = bf16_rne(x);
        h[j] = (short)hh;
        l[j] = (short)bf16_rne(x - bf16_to_f(hh));
    }
    dhi[idx] = h;
    dlo[idx] = l;
}

// ---------------------------------------------------------------------------
// Register GEMM core (bf16x3): 128x128 block tile, 4 independent waves each
// owning a 64x64 quadrant. NO LDS, NO barriers. SINGLE-buffered fragments
// (64 VGPR) + __launch_bounds__(256,3) -> 3 waves/SIMD: latency hidden by
// TLP instead of double-buffer ILP.
// ---------------------------------------------------------------------------
struct FragSet { short8 ah[4], al[4], bh[4], bl[4]; };

__device__ __forceinline__ void frag_load(FragSet& f,
        const short8* __restrict__ Afh, const short8* __restrict__ Afl,
        const short8* __restrict__ Bfh, const short8* __restrict__ Bfl,
        int aBase, int bBase, int kc) {
    int ak = aBase + kc * 64;
    int bk = bBase + kc * 64;
#pragma unroll
    for (int i = 0; i < 4; i++) {
        f.ah[i] = Afh[ak + i * 1216];   // 1216 = 19*64 short8 per row-block
        f.al[i] = Afl[ak + i * 1216];
        f.bh[i] = Bfh[bk + i * 1216];
        f.bl[i] = Bfl[bk + i * 1216];
    }
}

__device__ __forceinline__ void frag_mfma(const FragSet& f, f32x4 acc[4][4]) {
#pragma unroll
    for (int i = 0; i < 4; i++)
#pragma unroll
        for (int j = 0; j < 4; j++) {
            acc[i][j] = __builtin_amdgcn_mfma_f32_16x16x32_bf16(f.ah[i], f.bh[j], acc[i][j], 0, 0, 0);
            acc[i][j] = __builtin_amdgcn_mfma_f32_16x16x32_bf16(f.ah[i], f.bl[j], acc[i][j], 0, 0, 0);
            acc[i][j] = __builtin_amdgcn_mfma_f32_16x16x32_bf16(f.al[i], f.bh[j], acc[i][j], 0, 0, 0);
        }
}

__device__ __forceinline__ void gemm_core_reg(
        const short8* __restrict__ Afh, const short8* __restrict__ Afl,
        const short8* __restrict__ Bfh, const short8* __restrict__ Bfl,
        int aBase, int bBase, f32x4 acc[4][4]) {
    for (int kc = 0; kc < 19; kc++) {
        FragSet f;
        frag_load(f, Afh, Afl, Bfh, Bfl, aBase, bBase, kc);
        frag_mfma(f, acc);
    }
}

// m204 bijective XCD swizzle
__device__ __forceinline__ void decode_wg(int ncb, int& rowblk, int& colblk) {
    int nwg  = gridDim.x;
    int orig = blockIdx.x;
    int q = nwg >> 3, r = nwg & 7;
    int xcd = orig & 7, rank = orig >> 3;
    int wgid = (xcd < r ? xcd * (q + 1) : r * (q + 1) + (xcd - r) * q) + rank;
    rowblk = wgid / ncb;
    colblk = wgid - rowblk * ncb;
}

// GEMM1: H = relu(A @ W1^T + b1) -> Hf (fragment-interleaved). grid Mb*5.
__global__ __launch_bounds__(256, 3) void k_gemm1r(
        const short8* __restrict__ Afh, const short8* __restrict__ Afl,
        const short8* __restrict__ Wfh, const short8* __restrict__ Wfl,
        const float* __restrict__ b1,
        ushortT* __restrict__ Hfh, ushortT* __restrict__ Hfl, int N) {
    int rowblk, colblk;
    decode_wg(5, rowblk, colblk);
    int row0 = rowblk * 128;
    int col0 = colblk * 128;
    int t = threadIdx.x, w = t >> 6, l = t & 63;
    int wr = w >> 1, wc = w & 1, fr = l & 15, fq = l >> 4;

    int aBase = (rowblk * 8 + wr * 4) * 1216 + l;
    int bBase = (colblk * 8 + wc * 4) * 1216 + l;
    f32x4 acc[4][4];
#pragma unroll
    for (int i = 0; i < 4; i++)
#pragma unroll
        for (int j = 0; j < 4; j++) acc[i][j] = f32x4{0.f, 0.f, 0.f, 0.f};
    gemm_core_reg(Afh, Afl, Wfh, Wfl, aBase, bBase, acc);

#pragma unroll
    for (int i = 0; i < 4; i++) {
#pragma unroll
        for (int j = 0; j < 4; j++) {
            int col = col0 + wc * 64 + j * 16 + fr;
            float bias = (col < 600) ? b1[col] : 0.f;
#pragma unroll
            for (int r = 0; r < 4; r++) {
                int row = row0 + wr * 64 + i * 16 + fq * 4 + r;
                if (row >= N) continue;
                if (col < 600) {
                    float x = fmaxf(acc[i][j][r] + bias, 0.f);
                    ushortT hh = bf16_rne(x);
                    size_t off = frag_off(row, col);
                    Hfh[off] = hh;
                    Hfl[off] = bf16_rne(x - bf16_to_f(hh));
                } else if (col < KP) {
                    size_t off = frag_off(row, col);
                    Hfh[off] = 0;
                    Hfl[off] = 0;
                }
            }
        }
    }
}

// GEMM2: energy += sum_col relu(H @ W2^T + b2) * W3. grid Mb*3.
__global__ __launch_bounds__(256, 3) void k_gemm2r(
        const short8* __restrict__ Afh, const short8* __restrict__ Afl,
        const short8* __restrict__ Wfh, const short8* __restrict__ Wfl,
        const float* __restrict__ b2, const float* __restrict__ W3,
        float* __restrict__ energy, int N) {
    __shared__ float sE[128];
    int rowblk, colblk;
    decode_wg(3, rowblk, colblk);
    int row0 = rowblk * 128;
    int col0 = colblk * 128;
    int t = threadIdx.x, w = t >> 6, l = t & 63;
    int wr = w >> 1, wc = w & 1, fr = l & 15, fq = l >> 4;

    int aBase = (rowblk * 8 + wr * 4) * 1216 + l;
    int bBase = (colblk * 8 + wc * 4) * 1216 + l;
    f32x4 acc[4][4];
#pragma unroll
    for (int i = 0; i < 4; i++)
#pragma unroll
        for (int j = 0; j < 4; j++) acc[i][j] = f32x4{0.f, 0.f, 0.f, 0.f};
    gemm_core_reg(Afh, Afl, Wfh, Wfl, aBase, bBase, acc);

    if (t < 128) sE[t] = 0.f;
    __syncthreads();
#pragma unroll
    for (int i = 0; i < 4; i++) {
        float p[4] = {0.f, 0.f, 0.f, 0.f};
#pragma unroll
        for (int j = 0; j < 4; j++) {
            int col = col0 + wc * 64 + j * 16 + fr;
            if (col < 300) {
                float bias = b2[col];
                float wv   = W3[col];
#pragma unroll
                for (int r = 0; r < 4; r++)
                    p[r] += fmaxf(acc[i][j][r] + bias, 0.f) * wv;
            }
        }
#pragma unroll
        for (int r = 0; r < 4; r++) {
            float v = p[r];
            v += __shfl_xor(v, 1, 64);
            v += __shfl_xor(v, 2, 64);
            v += __shfl_xor(v, 4, 64);
            v += __shfl_xor(v, 8, 64);
            p[r] = v;
        }
        if (fr == 0) {
#pragma unroll
            for (int r = 0; r < 4; r++)
                atomicAdd(&sE[wr * 64 + i * 16 + fq * 4 + r], p[r]);
        }
    }
    __syncthreads();
    if (t < 128) {
        int row = row0 + t;
        if (row < N) atomicAdd(&energy[row], sE[t]);
    }
}

// ---------------------------------------------------------------------------
// K5: per-graph pool. batch sorted -> wave-segmented reduce, few atomics.
// ---------------------------------------------------------------------------
__global__ void k_pool(const float* __restrict__ energy, const int* __restrict__ batch,
                       float* __restrict__ dg, int N) {
    int i = blockIdx.x * blockDim.x + threadIdx.x;
    int lane = threadIdx.x & 63;
    float v = (i < N) ? energy[i] : 0.f;
    int   b = (i < N) ? batch[i]  : -1;
#pragma unroll
    for (int off = 1; off < 64; off <<= 1) {
        float vv = __shfl_down(v, off, 64);
        int   bb = __shfl_down(b, off, 64);
        if (lane + off < 64 && bb == b) v += vv;
    }
    int pb = __shfl_up(b, 1, 64);
    if (i < N && (lane == 0 || pb != b)) atomicAdd(&dg[b], v);
}

extern "C" void kernel_launch(void* const* d_in, const int* in_sizes, int n_in,
                              void* d_out, int out_size, void* d_ws, size_t ws_size,
                              hipStream_t stream) {
    const int* atom       = (const int*)d_in[0];
    const int* bond_index = (const int*)d_in[1];
    const int* bond_attr  = (const int*)d_in[2];
    const int* batch      = (const int*)d_in[3];
    const float* Wa   = (const float*)d_in[4];
    const float* Wh   = (const float*)d_in[5];
    const float* War  = (const float*)d_in[6];
    const float* Wc   = (const float*)d_in[7];
    const float* Wch  = (const float*)d_in[8];
    const float* Wbt  = (const float*)d_in[9];
    const float* Wbai = (const float*)d_in[10];
    const float* Wsla = (const float*)d_in[11];
    const float* Wsl  = (const float*)d_in[12];
    const float* W1   = (const float*)d_in[13];
    const float* b1   = (const float*)d_in[14];
    const float* W2   = (const float*)d_in[15];
    const float* b2   = (const float*)d_in[16];
    const float* W3   = (const float*)d_in[17];

    int N = in_sizes[0] / 5;   // 50000
    int E = in_sizes[1] / 2;   // 100000
    int Mb = (N + 127) / 128;  // 391
    int Npad = Mb * 128;       // 50048
    int nTiles = Npad / 16;    // 3128 row-blocks

    size_t regionBytes = (size_t)Npad * KP * 4;
    char* base = (char*)d_ws;
    float* nodeA = (float*)base;                       // region0: embed out, mp1 in
    float* nodeB = (float*)(base + regionBytes);       // region1: mp1 out, mp2 in
    short8* Afh = (short8*)nodeA;
    short8* Afl = Afh + (size_t)nTiles * 1216;
    short8* Hfh = (short8*)nodeB;
    short8* Hfl = Hfh + (size_t)nTiles * 1216;
    char* tail = base + 2 * regionBytes;
    float* energy  = (float*)tail;
    int* counts    = (int*)(energy + N);
    int* offsets   = counts + N;
    int* cursor    = offsets + N;
    int* edge_list = cursor + N;
    short8* W1fh   = (short8*)(edge_list + E);         // 40*19*64 tiles
    short8* W1fl   = W1fh + 40 * 19 * 64;
    short8* W2fh   = W1fl + 40 * 19 * 64;              // 24*19*64 tiles
    short8* W2fl   = W2fh + 24 * 19 * 64;

    const int* bsrc = bond_index;
    const int* bdst = bond_index + E;

    // CSR build (dst -> edges)
    hipMemsetAsync(counts, 0, (size_t)N * sizeof(int), stream);
    k_hist<<<(E + 255) / 256, 256, 0, stream>>>(bdst, counts, E);
    k_scan<<<1, 1024, 0, stream>>>(counts, offsets, cursor, N);
    k_scatter<<<(E + 255) / 256, 256, 0, stream>>>(bdst, cursor, edge_list, E);

    // weight splits to fragment-interleaved layout
    k_split_w_frag<<<(40 * 19 * 64 + 255) / 256, 256, 0, stream>>>(W1, W1fh, W1fl, 600, 40);
    k_split_w_frag<<<(24 * 19 * 64 + 255) / 256, 256, 0, stream>>>(W2, W2fh, W2fl, 300, 24);

    // K1: node embedding -> nodeA
    {
        int total = N * Q4;
        k_node_embed<<<(total + 255) / 256, 256, 0, stream>>>(
            atom, (const float4*)Wa, (const float4*)Wh, (const float4*)War,
            (const float4*)Wc, (const float4*)Wch, (float4*)nodeA, N);
    }

    int mpblocks = (N * 64 + 255) / 256;
    // round 1: nodeA -> nodeB (fp32)
    k_mp_gather<<<mpblocks, 256, 0, stream>>>(bsrc, bond_attr, atom,
        offsets, counts, edge_list,
        (const float4*)Wbt, (const float4*)Wbai, (const float4*)Wsla, (const float4*)Wsl,
        (const float4*)nodeA, (float4*)nodeB, N);

    // zero A-frag pad tiles (rows N..Npad; region0 is dead fp32 now)
    {
        int firstPad = N / 16;
        size_t offB  = (size_t)firstPad * 1216 * 16;
        size_t cntB  = (size_t)(nTiles - firstPad) * 1216 * 16;
        if (cntB) {
            hipMemsetAsync((char*)Afh + offB, 0, cntB, stream);
            hipMemsetAsync((char*)Afl + offB, 0, cntB, stream);
        }
    }

    // round 2 fused with relu+split into fragment layout: nodeB -> Afh/Afl
    k_mp_gather_rs<<<mpblocks, 256, 0, stream>>>(bsrc, bond_attr, atom,
        offsets, counts, edge_list,
        (const float4*)Wbt, (const float4*)Wbai, (const float4*)Wsla, (const float4*)Wsl,
        (const float4*)nodeB, (ushortT*)Afh, (ushortT*)Afl, N);

    // GEMM1: Af x W1f -> Hf (region1; nodeB dead)
    k_gemm1r<<<Mb * 5, 256, 0, stream>>>(Afh, Afl, W1fh, W1fl, b1,
                                         (ushortT*)Hfh, (ushortT*)Hfl, N);

    // GEMM2: Hf x W2f (+b2, W3) -> energy (atomic accumulate)
    hipMemsetAsync(energy, 0, (size_t)N * sizeof(float), stream);
    k_gemm2r<<<Mb * 3, 256, 0, stream>>>(Hfh, Hfl, W2fh, W2fl, b2, W3, energy, N);

    // pool
    hipMemsetAsync(d_out, 0, (size_t)out_size * sizeof(float), stream);
    k_pool<<<(N + 255) / 256, 256, 0, stream>>>(energy, batch, (float*)d_out, N);
}

// Round 10
// 582.225 us; speedup vs baseline: 1.0899x; 1.0040x over previous
//
#include <hip/hip_runtime.h>

#define EMB 600
#define Q4  150   // EMB / 4
#define KP  608   // K padded (19 * 32)

typedef unsigned short ushortT;
typedef __attribute__((ext_vector_type(8))) short short8;
typedef __attribute__((ext_vector_type(4))) short short4v;
typedef __attribute__((ext_vector_type(4))) float f32x4;

__device__ __forceinline__ float4 f4add(float4 a, float4 b) {
    return make_float4(a.x + b.x, a.y + b.y, a.z + b.z, a.w + b.w);
}
__device__ __forceinline__ float4 f4fma(float4 acc, float4 v, float4 e) {
    return make_float4(fmaf(v.x, e.x, acc.x), fmaf(v.y, e.y, acc.y),
                       fmaf(v.z, e.z, acc.z), fmaf(v.w, e.w, acc.w));
}
__device__ __forceinline__ ushortT bf16_rne(float x) {
    unsigned u = __float_as_uint(x);
    return (ushortT)((u + 0x7fffu + ((u >> 16) & 1u)) >> 16);
}
__device__ __forceinline__ float bf16_to_f(ushortT h) {
    return __uint_as_float(((unsigned)h) << 16);
}

// fragment-interleaved offset (ushort units) for element (row, col)
__device__ __forceinline__ size_t frag_off(int row, int col) {
    return ((size_t)((row >> 4) * 19 + (col >> 5)) * 64
            + (row & 15) + 16 * ((col >> 3) & 3)) * 8 + (col & 7);
}

// ---------------------------------------------------------------------------
// K1: node embedding = sum of 5 table lookups.
// ---------------------------------------------------------------------------
__global__ void k_node_embed(const int* __restrict__ atom,
                             const float4* __restrict__ Wa,
                             const float4* __restrict__ Wh,
                             const float4* __restrict__ War,
                             const float4* __restrict__ Wc,
                             const float4* __restrict__ Wch,
                             float4* __restrict__ out, int N) {
    int idx = blockIdx.x * blockDim.x + threadIdx.x;
    int total = N * Q4;
    if (idx >= total) return;
    int n = idx / Q4;
    int q = idx - n * Q4;
    const int* a = atom + n * 5;
    float4 r = Wa[a[0] * Q4 + q];
    r = f4add(r, Wh [a[1] * Q4 + q]);
    r = f4add(r, War[a[2] * Q4 + q]);
    r = f4add(r, Wc [a[3] * Q4 + q]);
    r = f4add(r, Wch[a[4] * Q4 + q]);
    out[idx] = r;
}

// ---------------------------------------------------------------------------
// CSR build: histogram -> scan -> scatter
// ---------------------------------------------------------------------------
__global__ void k_hist(const int* __restrict__ bdst, int* __restrict__ counts, int E) {
    int i = blockIdx.x * blockDim.x + threadIdx.x;
    if (i < E) atomicAdd(&counts[bdst[i]], 1);
}

__global__ __launch_bounds__(1024) void k_scan(const int* __restrict__ counts,
                                               int* __restrict__ offsets,
                                               int* __restrict__ cursor, int N) {
    __shared__ int sums[1024];
    int t = threadIdx.x;
    int chunk = (N + 1023) / 1024;
    int begin = t * chunk;
    int end = begin + chunk; if (end > N) end = N;
    int s = 0;
    for (int i = begin; i < end; i++) s += counts[i];
    sums[t] = s;
    __syncthreads();
    for (int off = 1; off < 1024; off <<= 1) {
        int v = (t >= off) ? sums[t - off] : 0;
        __syncthreads();
        sums[t] += v;
        __syncthreads();
    }
    int run = (t == 0) ? 0 : sums[t - 1];
    for (int i = begin; i < end; i++) {
        offsets[i] = run;
        cursor[i]  = run;
        run += counts[i];
    }
}

__global__ void k_scatter(const int* __restrict__ bdst, int* __restrict__ cursor,
                          int* __restrict__ edge_list, int E) {
    int i = blockIdx.x * blockDim.x + threadIdx.x;
    if (i < E) {
        int pos = atomicAdd(&cursor[bdst[i]], 1);
        edge_list[pos] = i;
    }
}

// ---------------------------------------------------------------------------
// K2a: MP round 1 (fp32 out). One wave per dest node. Edge-meta prefetch.
// ---------------------------------------------------------------------------
__global__ __launch_bounds__(256) void k_mp_gather(
        const int* __restrict__ bsrc, const int* __restrict__ battr,
        const int* __restrict__ atom,
        const int* __restrict__ offsets, const int* __restrict__ counts,
        const int* __restrict__ edge_list,
        const float4* __restrict__ Wbt, const float4* __restrict__ Wbai,
        const float4* __restrict__ Wsla, const float4* __restrict__ Wsl,
        const float4* __restrict__ in, float4* __restrict__ out, int N) {
    int wid  = (int)((blockIdx.x * blockDim.x + threadIdx.x) >> 6);
    int lane = threadIdx.x & 63;
    if (wid >= N) return;
    int d = wid;
    int q0 = lane, q1 = lane + 64, q2 = lane + 128;
    bool has2 = (q2 < Q4);

    int start = offsets[d], cnt = counts[d];
    int s = 0, t0 = 0, t1 = 0;
    if (cnt > 0) {
        int eid = edge_list[start];
        s  = bsrc[eid];
        t0 = battr[eid * 2 + 0];
        t1 = battr[eid * 2 + 1];
    }

    const float4* slA = Wsla + atom[d * 5] * Q4;
    const float4* inr = in + (size_t)d * Q4;
    float4 acc0 = make_float4(0, 0, 0, 0), acc1 = acc0, acc2 = acc0;
    acc0 = f4fma(acc0, inr[q0], f4add(slA[q0], Wsl[q0]));
    acc1 = f4fma(acc1, inr[q1], f4add(slA[q1], Wsl[q1]));
    if (has2) acc2 = f4fma(acc2, inr[q2], f4add(slA[q2], Wsl[q2]));

    for (int k = 0; k < cnt; k++) {
        int ns = s, nt0 = t0, nt1 = t1;
        if (k + 1 < cnt) {
            int ne = edge_list[start + k + 1];
            ns  = bsrc[ne];
            nt0 = battr[ne * 2 + 0];
            nt1 = battr[ne * 2 + 1];
        }
        const float4* e0 = Wbt  + t0 * Q4;
        const float4* e1 = Wbai + t1 * Q4;
        const float4* sr = in + (size_t)s * Q4;
        acc0 = f4fma(acc0, sr[q0], f4add(e0[q0], e1[q0]));
        acc1 = f4fma(acc1, sr[q1], f4add(e0[q1], e1[q1]));
        if (has2) acc2 = f4fma(acc2, sr[q2], f4add(e0[q2], e1[q2]));
        s = ns; t0 = nt0; t1 = nt1;
    }
    float4* orow = out + (size_t)d * Q4;
    orow[q0] = acc0;
    orow[q1] = acc1;
    if (has2) orow[q2] = acc2;
}

// ---------------------------------------------------------------------------
// K2b: MP round 2 fused with relu + bf16 hi/lo split, fragment-interleaved out.
// ---------------------------------------------------------------------------
__device__ __forceinline__ void frag_store4(ushortT* __restrict__ hi,
                                            ushortT* __restrict__ lo,
                                            int d, int q, float4 v) {
    int kc = q >> 3, ks = (q >> 1) & 3, half = q & 1;
    size_t off = ((size_t)((d >> 4) * 19 + kc) * 64 + (d & 15) + 16 * ks) * 8
                 + half * 4;
    float vv[4] = {v.x, v.y, v.z, v.w};
    short4v h4, l4;
#pragma unroll
    for (int j = 0; j < 4; j++) {
        float x = fmaxf(vv[j], 0.f);
        ushortT hh = bf16_rne(x);
        h4[j] = (short)hh;
        l4[j] = (short)bf16_rne(x - bf16_to_f(hh));
    }
    *(short4v*)(hi + off) = h4;
    *(short4v*)(lo + off) = l4;
}

__global__ __launch_bounds__(256) void k_mp_gather_rs(
        const int* __restrict__ bsrc, const int* __restrict__ battr,
        const int* __restrict__ atom,
        const int* __restrict__ offsets, const int* __restrict__ counts,
        const int* __restrict__ edge_list,
        const float4* __restrict__ Wbt, const float4* __restrict__ Wbai,
        const float4* __restrict__ Wsla, const float4* __restrict__ Wsl,
        const float4* __restrict__ in,
        ushortT* __restrict__ hi, ushortT* __restrict__ lo, int N) {
    int wid  = (int)((blockIdx.x * blockDim.x + threadIdx.x) >> 6);
    int lane = threadIdx.x & 63;
    if (wid >= N) return;
    int d = wid;
    int q0 = lane, q1 = lane + 64, q2 = lane + 128;
    bool has2 = (q2 < Q4);

    int start = offsets[d], cnt = counts[d];
    int s = 0, t0 = 0, t1 = 0;
    if (cnt > 0) {
        int eid = edge_list[start];
        s  = bsrc[eid];
        t0 = battr[eid * 2 + 0];
        t1 = battr[eid * 2 + 1];
    }

    const float4* slA = Wsla + atom[d * 5] * Q4;
    const float4* inr = in + (size_t)d * Q4;
    float4 acc0 = make_float4(0, 0, 0, 0), acc1 = acc0, acc2 = acc0;
    acc0 = f4fma(acc0, inr[q0], f4add(slA[q0], Wsl[q0]));
    acc1 = f4fma(acc1, inr[q1], f4add(slA[q1], Wsl[q1]));
    if (has2) acc2 = f4fma(acc2, inr[q2], f4add(slA[q2], Wsl[q2]));

    for (int k = 0; k < cnt; k++) {
        int ns = s, nt0 = t0, nt1 = t1;
        if (k + 1 < cnt) {
            int ne = edge_list[start + k + 1];
            ns  = bsrc[ne];
            nt0 = battr[ne * 2 + 0];
            nt1 = battr[ne * 2 + 1];
        }
        const float4* e0 = Wbt  + t0 * Q4;
        const float4* e1 = Wbai + t1 * Q4;
        const float4* sr = in + (size_t)s * Q4;
        acc0 = f4fma(acc0, sr[q0], f4add(e0[q0], e1[q0]));
        acc1 = f4fma(acc1, sr[q1], f4add(e0[q1], e1[q1]));
        if (has2) acc2 = f4fma(acc2, sr[q2], f4add(e0[q2], e1[q2]));
        s = ns; t0 = nt0; t1 = nt1;
    }
    frag_store4(hi, lo, d, q0, acc0);
    frag_store4(hi, lo, d, q1, acc1);
    if (has2) frag_store4(hi, lo, d, q2, acc2);
    if (lane == 31) {   // zero K-pad cols 600..607 (kc=18, ks=3 slot)
        size_t off = ((size_t)((d >> 4) * 19 + 18) * 64 + (d & 15) + 48) * 8;
        short8 z = {0, 0, 0, 0, 0, 0, 0, 0};
        *(short8*)(hi + off) = z;
        *(short8*)(lo + off) = z;
    }
}

// ---------------------------------------------------------------------------
// Weight split to FRAGMENT-INTERLEAVED layout.
// ---------------------------------------------------------------------------
__global__ void k_split_w_frag(const float* __restrict__ src,
                               short8* __restrict__ dhi, short8* __restrict__ dlo,
                               int rows_in, int cb_count) {
    int idx = blockIdx.x * blockDim.x + threadIdx.x;
    int total = cb_count * 19 * 64;
    if (idx >= total) return;
    int lane = idx & 63;
    int tile = idx >> 6;
    int cb = tile / 19, kc = tile - cb * 19;
    int col = cb * 16 + (lane & 15);
    int k0  = kc * 32 + (lane >> 4) * 8;
    short8 h, l;
#pragma unroll
    for (int j = 0; j < 8; j++) {
        int k = k0 + j;
        float x = (col < rows_in && k < 600) ? src[(size_t)col * 600 + k] : 0.f;
        ushortT hh = bf16_rne(x);
        h[j] = (short)hh;
        l[j] = (short)bf16_rne(x - bf16_to_f(hh));
    }
    dhi[idx] = h;
    dlo[idx] = l;
}

// ---------------------------------------------------------------------------
// Register GEMM core (bf16x3): 128x128 block tile, 4 independent waves each
// owning a 64x64 quadrant. NO LDS, NO barriers. Single-buffered fragments,
// __launch_bounds__(256,4) -> 4 waves/SIMD (60 arch + 64 acc = 124 <= 128).
// ---------------------------------------------------------------------------
struct FragSet { short8 ah[4], al[4], bh[4], bl[4]; };

__device__ __forceinline__ void frag_load(FragSet& f,
        const short8* __restrict__ Afh, const short8* __restrict__ Afl,
        const short8* __restrict__ Bfh, const short8* __restrict__ Bfl,
        int aBase, int bBase, int kc) {
    int ak = aBase + kc * 64;
    int bk = bBase + kc * 64;
#pragma unroll
    for (int i = 0; i < 4; i++) {
        f.ah[i] = Afh[ak + i * 1216];   // 1216 = 19*64 short8 per row-block
        f.al[i] = Afl[ak + i * 1216];
        f.bh[i] = Bfh[bk + i * 1216];
        f.bl[i] = Bfl[bk + i * 1216];
    }
}

__device__ __forceinline__ void frag_mfma(const FragSet& f, f32x4 acc[4][4]) {
#pragma unroll
    for (int i = 0; i < 4; i++)
#pragma unroll
        for (int j = 0; j < 4; j++) {
            acc[i][j] = __builtin_amdgcn_mfma_f32_16x16x32_bf16(f.ah[i], f.bh[j], acc[i][j], 0, 0, 0);
            acc[i][j] = __builtin_amdgcn_mfma_f32_16x16x32_bf16(f.ah[i], f.bl[j], acc[i][j], 0, 0, 0);
            acc[i][j] = __builtin_amdgcn_mfma_f32_16x16x32_bf16(f.al[i], f.bh[j], acc[i][j], 0, 0, 0);
        }
}

__device__ __forceinline__ void gemm_core_reg(
        const short8* __restrict__ Afh, const short8* __restrict__ Afl,
        const short8* __restrict__ Bfh, const short8* __restrict__ Bfl,
        int aBase, int bBase, f32x4 acc[4][4]) {
    for (int kc = 0; kc < 19; kc++) {
        FragSet f;
        frag_load(f, Afh, Afl, Bfh, Bfl, aBase, bBase, kc);
        frag_mfma(f, acc);
    }
}

// m204 bijective XCD swizzle
__device__ __forceinline__ void decode_wg(int ncb, int& rowblk, int& colblk) {
    int nwg  = gridDim.x;
    int orig = blockIdx.x;
    int q = nwg >> 3, r = nwg & 7;
    int xcd = orig & 7, rank = orig >> 3;
    int wgid = (xcd < r ? xcd * (q + 1) : r * (q + 1) + (xcd - r) * q) + rank;
    rowblk = wgid / ncb;
    colblk = wgid - rowblk * ncb;
}

// GEMM1: H = relu(A @ W1^T + b1) -> Hf (fragment-interleaved). grid Mb*5.
__global__ __launch_bounds__(256, 4) void k_gemm1r(
        const short8* __restrict__ Afh, const short8* __restrict__ Afl,
        const short8* __restrict__ Wfh, const short8* __restrict__ Wfl,
        const float* __restrict__ b1,
        ushortT* __restrict__ Hfh, ushortT* __restrict__ Hfl, int N) {
    int rowblk, colblk;
    decode_wg(5, rowblk, colblk);
    int row0 = rowblk * 128;
    int col0 = colblk * 128;
    int t = threadIdx.x, w = t >> 6, l = t & 63;
    int wr = w >> 1, wc = w & 1, fr = l & 15, fq = l >> 4;

    int aBase = (rowblk * 8 + wr * 4) * 1216 + l;
    int bBase = (colblk * 8 + wc * 4) * 1216 + l;
    f32x4 acc[4][4];
#pragma unroll
    for (int i = 0; i < 4; i++)
#pragma unroll
        for (int j = 0; j < 4; j++) acc[i][j] = f32x4{0.f, 0.f, 0.f, 0.f};
    gemm_core_reg(Afh, Afl, Wfh, Wfl, aBase, bBase, acc);

#pragma unroll
    for (int i = 0; i < 4; i++) {
#pragma unroll
        for (int j = 0; j < 4; j++) {
            int col = col0 + wc * 64 + j * 16 + fr;
            float bias = (col < 600) ? b1[col] : 0.f;
#pragma unroll
            for (int r = 0; r < 4; r++) {
                int row = row0 + wr * 64 + i * 16 + fq * 4 + r;
                if (row >= N) continue;
                if (col < 600) {
                    float x = fmaxf(acc[i][j][r] + bias, 0.f);
                    ushortT hh = bf16_rne(x);
                    size_t off = frag_off(row, col);
                    Hfh[off] = hh;
                    Hfl[off] = bf16_rne(x - bf16_to_f(hh));
                } else if (col < KP) {
                    size_t off = frag_off(row, col);
                    Hfh[off] = 0;
                    Hfl[off] = 0;
                }
            }
        }
    }
}

// GEMM2: energy += sum_col relu(H @ W2^T + b2) * W3. grid Mb*3.
__global__ __launch_bounds__(256, 4) void k_gemm2r(
        const short8* __restrict__ Afh, const short8* __restrict__ Afl,
        const short8* __restrict__ Wfh, const short8* __restrict__ Wfl,
        const float* __restrict__ b2, const float* __restrict__ W3,
        float* __restrict__ energy, int N) {
    __shared__ float sE[128];
    int rowblk, colblk;
    decode_wg(3, rowblk, colblk);
    int row0 = rowblk * 128;
    int col0 = colblk * 128;
    int t = threadIdx.x, w = t >> 6, l = t & 63;
    int wr = w >> 1, wc = w & 1, fr = l & 15, fq = l >> 4;

    int aBase = (rowblk * 8 + wr * 4) * 1216 + l;
    int bBase = (colblk * 8 + wc * 4) * 1216 + l;
    f32x4 acc[4][4];
#pragma unroll
    for (int i = 0; i < 4; i++)
#pragma unroll
        for (int j = 0; j < 4; j++) acc[i][j] = f32x4{0.f, 0.f, 0.f, 0.f};
    gemm_core_reg(Afh, Afl, Wfh, Wfl, aBase, bBase, acc);

    if (t < 128) sE[t] = 0.f;
    __syncthreads();
#pragma unroll
    for (int i = 0; i < 4; i++) {
        float p[4] = {0.f, 0.f, 0.f, 0.f};
#pragma unroll
        for (int j = 0; j < 4; j++) {
            int col = col0 + wc * 64 + j * 16 + fr;
            if (col < 300) {
                float bias = b2[col];
                float wv   = W3[col];
#pragma unroll
                for (int r = 0; r < 4; r++)
                    p[r] += fmaxf(acc[i][j][r] + bias, 0.f) * wv;
            }
        }
#pragma unroll
        for (int r = 0; r < 4; r++) {
            float v = p[r];
            v += __shfl_xor(v, 1, 64);
            v += __shfl_xor(v, 2, 64);
            v += __shfl_xor(v, 4, 64);
            v += __shfl_xor(v, 8, 64);
            p[r] = v;
        }
        if (fr == 0) {
#pragma unroll
            for (int r = 0; r < 4; r++)
                atomicAdd(&sE[wr * 64 + i * 16 + fq * 4 + r], p[r]);
        }
    }
    __syncthreads();
    if (t < 128) {
        int row = row0 + t;
        if (row < N) atomicAdd(&energy[row], sE[t]);
    }
}

// ---------------------------------------------------------------------------
// K5: per-graph pool. batch sorted -> wave-segmented reduce, few atomics.
// ---------------------------------------------------------------------------
__global__ void k_pool(const float* __restrict__ energy, const int* __restrict__ batch,
                       float* __restrict__ dg, int N) {
    int i = blockIdx.x * blockDim.x + threadIdx.x;
    int lane = threadIdx.x & 63;
    float v = (i < N) ? energy[i] : 0.f;
    int   b = (i < N) ? batch[i]  : -1;
#pragma unroll
    for (int off = 1; off < 64; off <<= 1) {
        float vv = __shfl_down(v, off, 64);
        int   bb = __shfl_down(b, off, 64);
        if (lane + off < 64 && bb == b) v += vv;
    }
    int pb = __shfl_up(b, 1, 64);
    if (i < N && (lane == 0 || pb != b)) atomicAdd(&dg[b], v);
}

extern "C" void kernel_launch(void* const* d_in, const int* in_sizes, int n_in,
                              void* d_out, int out_size, void* d_ws, size_t ws_size,
                              hipStream_t stream) {
    const int* atom       = (const int*)d_in[0];
    const int* bond_index = (const int*)d_in[1];
    const int* bond_attr  = (const int*)d_in[2];
    const int* batch      = (const int*)d_in[3];
    const float* Wa   = (const float*)d_in[4];
    const float* Wh   = (const float*)d_in[5];
    const float* War  = (const float*)d_in[6];
    const float* Wc   = (const float*)d_in[7];
    const float* Wch  = (const float*)d_in[8];
    const float* Wbt  = (const float*)d_in[9];
    const float* Wbai = (const float*)d_in[10];
    const float* Wsla = (const float*)d_in[11];
    const float* Wsl  = (const float*)d_in[12];
    const float* W1   = (const float*)d_in[13];
    const float* b1   = (const float*)d_in[14];
    const float* W2   = (const float*)d_in[15];
    const float* b2   = (const float*)d_in[16];
    const float* W3   = (const float*)d_in[17];

    int N = in_sizes[0] / 5;   // 50000
    int E = in_sizes[1] / 2;   // 100000
    int Mb = (N + 127) / 128;  // 391
    int Npad = Mb * 128;       // 50048
    int nTiles = Npad / 16;    // 3128 row-blocks

    size_t regionBytes = (size_t)Npad * KP * 4;
    char* base = (char*)d_ws;
    float* nodeA = (float*)base;                       // region0: embed out, mp1 in
    float* nodeB = (float*)(base + regionBytes);       // region1: mp1 out, mp2 in
    short8* Afh = (short8*)nodeA;
    short8* Afl = Afh + (size_t)nTiles * 1216;
    short8* Hfh = (short8*)nodeB;
    short8* Hfl = Hfh + (size_t)nTiles * 1216;
    char* tail = base + 2 * regionBytes;
    float* energy  = (float*)tail;
    int* counts    = (int*)(energy + N);
    int* offsets   = counts + N;
    int* cursor    = offsets + N;
    int* edge_list = cursor + N;
    short8* W1fh   = (short8*)(edge_list + E);         // 40*19*64 tiles
    short8* W1fl   = W1fh + 40 * 19 * 64;
    short8* W2fh   = W1fl + 40 * 19 * 64;              // 24*19*64 tiles
    short8* W2fl   = W2fh + 24 * 19 * 64;

    const int* bsrc = bond_index;
    const int* bdst = bond_index + E;

    // CSR build (dst -> edges)
    hipMemsetAsync(counts, 0, (size_t)N * sizeof(int), stream);
    k_hist<<<(E + 255) / 256, 256, 0, stream>>>(bdst, counts, E);
    k_scan<<<1, 1024, 0, stream>>>(counts, offsets, cursor, N);
    k_scatter<<<(E + 255) / 256, 256, 0, stream>>>(bdst, cursor, edge_list, E);

    // weight splits to fragment-interleaved layout
    k_split_w_frag<<<(40 * 19 * 64 + 255) / 256, 256, 0, stream>>>(W1, W1fh, W1fl, 600, 40);
    k_split_w_frag<<<(24 * 19 * 64 + 255) / 256, 256, 0, stream>>>(W2, W2fh, W2fl, 300, 24);

    // K1: node embedding -> nodeA
    {
        int total = N * Q4;
        k_node_embed<<<(total + 255) / 256, 256, 0, stream>>>(
            atom, (const float4*)Wa, (const float4*)Wh, (const float4*)War,
            (const float4*)Wc, (const float4*)Wch, (float4*)nodeA, N);
    }

    int mpblocks = (N * 64 + 255) / 256;
    // round 1: nodeA -> nodeB (fp32)
    k_mp_gather<<<mpblocks, 256, 0, stream>>>(bsrc, bond_attr, atom,
        offsets, counts, edge_list,
        (const float4*)Wbt, (const float4*)Wbai, (const float4*)Wsla, (const float4*)Wsl,
        (const float4*)nodeA, (float4*)nodeB, N);

    // zero A-frag pad tiles (rows N..Npad; region0 is dead fp32 now)
    {
        int firstPad = N / 16;
        size_t offB  = (size_t)firstPad * 1216 * 16;
        size_t cntB  = (size_t)(nTiles - firstPad) * 1216 * 16;
        if (cntB) {
            hipMemsetAsync((char*)Afh + offB, 0, cntB, stream);
            hipMemsetAsync((char*)Afl + offB, 0, cntB, stream);
        }
    }

    // round 2 fused with relu+split into fragment layout: nodeB -> Afh/Afl
    k_mp_gather_rs<<<mpblocks, 256, 0, stream>>>(bsrc, bond_attr, atom,
        offsets, counts, edge_list,
        (const float4*)Wbt, (const float4*)Wbai, (const float4*)Wsla, (const float4*)Wsl,
        (const float4*)nodeB, (ushortT*)Afh, (ushortT*)Afl, N);

    // GEMM1: Af x W1f -> Hf (region1; nodeB dead)
    k_gemm1r<<<Mb * 5, 256, 0, stream>>>(Afh, Afl, W1fh, W1fl, b1,
                                         (ushortT*)Hfh, (ushortT*)Hfl, N);

    // GEMM2: Hf x W2f (+b2, W3) -> energy (atomic accumulate)
    hipMemsetAsync(energy, 0, (size_t)N * sizeof(float), stream);
    k_gemm2r<<<Mb * 3, 256, 0, stream>>>(Hfh, Hfl, W2fh, W2fl, b2, W3, energy, N);

    // pool
    hipMemsetAsync(d_out, 0, (size_t)out_size * sizeof(float), stream);
    k_pool<<<(N + 255) / 256, 256, 0, stream>>>(energy, batch, (float*)d_out, N);
}

// Round 11
// 490.973 us; speedup vs baseline: 1.2925x; 1.1859x over previous
//
#include <hip/hip_runtime.h>

#define EMB 600
#define Q4  150   // EMB / 4
#define KP  608   // K padded (19 * 32)

typedef unsigned short ushortT;
typedef __attribute__((ext_vector_type(8))) short short8;
typedef __attribute__((ext_vector_type(4))) short short4v;
typedef __attribute__((ext_vector_type(4))) float f32x4;

__device__ __forceinline__ float4 f4add(float4 a, float4 b) {
    return make_float4(a.x + b.x, a.y + b.y, a.z + b.z, a.w + b.w);
}
__device__ __forceinline__ float4 f4fma(float4 acc, float4 v, float4 e) {
    return make_float4(fmaf(v.x, e.x, acc.x), fmaf(v.y, e.y, acc.y),
                       fmaf(v.z, e.z, acc.z), fmaf(v.w, e.w, acc.w));
}
__device__ __forceinline__ ushortT bf16_rne(float x) {
    unsigned u = __float_as_uint(x);
    return (ushortT)((u + 0x7fffu + ((u >> 16) & 1u)) >> 16);
}
__device__ __forceinline__ float bf16_to_f(ushortT h) {
    return __uint_as_float(((unsigned)h) << 16);
}

// fragment-interleaved offset (ushort units) for element (row, col)
__device__ __forceinline__ size_t frag_off(int row, int col) {
    return ((size_t)((row >> 4) * 19 + (col >> 5)) * 64
            + (row & 15) + 16 * ((col >> 3) & 3)) * 8 + (col & 7);
}

// ---------------------------------------------------------------------------
// K1: node embedding = sum of 5 table lookups.
// ---------------------------------------------------------------------------
__global__ void k_node_embed(const int* __restrict__ atom,
                             const float4* __restrict__ Wa,
                             const float4* __restrict__ Wh,
                             const float4* __restrict__ War,
                             const float4* __restrict__ Wc,
                             const float4* __restrict__ Wch,
                             float4* __restrict__ out, int N) {
    int idx = blockIdx.x * blockDim.x + threadIdx.x;
    int total = N * Q4;
    if (idx >= total) return;
    int n = idx / Q4;
    int q = idx - n * Q4;
    const int* a = atom + n * 5;
    float4 r = Wa[a[0] * Q4 + q];
    r = f4add(r, Wh [a[1] * Q4 + q]);
    r = f4add(r, War[a[2] * Q4 + q]);
    r = f4add(r, Wc [a[3] * Q4 + q]);
    r = f4add(r, Wch[a[4] * Q4 + q]);
    out[idx] = r;
}

// ---------------------------------------------------------------------------
// CSR build: histogram -> scan -> scatter
// ---------------------------------------------------------------------------
__global__ void k_hist(const int* __restrict__ bdst, int* __restrict__ counts, int E) {
    int i = blockIdx.x * blockDim.x + threadIdx.x;
    if (i < E) atomicAdd(&counts[bdst[i]], 1);
}

__global__ __launch_bounds__(1024) void k_scan(const int* __restrict__ counts,
                                               int* __restrict__ offsets,
                                               int* __restrict__ cursor, int N) {
    __shared__ int sums[1024];
    int t = threadIdx.x;
    int chunk = (N + 1023) / 1024;
    int begin = t * chunk;
    int end = begin + chunk; if (end > N) end = N;
    int s = 0;
    for (int i = begin; i < end; i++) s += counts[i];
    sums[t] = s;
    __syncthreads();
    for (int off = 1; off < 1024; off <<= 1) {
        int v = (t >= off) ? sums[t - off] : 0;
        __syncthreads();
        sums[t] += v;
        __syncthreads();
    }
    int run = (t == 0) ? 0 : sums[t - 1];
    for (int i = begin; i < end; i++) {
        offsets[i] = run;
        cursor[i]  = run;
        run += counts[i];
    }
}

__global__ void k_scatter(const int* __restrict__ bdst, int* __restrict__ cursor,
                          int* __restrict__ edge_list, int E) {
    int i = blockIdx.x * blockDim.x + threadIdx.x;
    if (i < E) {
        int pos = atomicAdd(&cursor[bdst[i]], 1);
        edge_list[pos] = i;
    }
}

// ---------------------------------------------------------------------------
// K2a: MP round 1 (fp32 out). TWO waves per dest node (75 float4 each) for
// 2x latency-hiding parallelism. Edge-meta prefetch.
// ---------------------------------------------------------------------------
__global__ __launch_bounds__(256) void k_mp_gather(
        const int* __restrict__ bsrc, const int* __restrict__ battr,
        const int* __restrict__ atom,
        const int* __restrict__ offsets, const int* __restrict__ counts,
        const int* __restrict__ edge_list,
        const float4* __restrict__ Wbt, const float4* __restrict__ Wbai,
        const float4* __restrict__ Wsla, const float4* __restrict__ Wsl,
        const float4* __restrict__ in, float4* __restrict__ out, int N) {
    int wid  = (int)((blockIdx.x * blockDim.x + threadIdx.x) >> 6);
    int lane = threadIdx.x & 63;
    int d    = wid >> 1;
    int half = wid & 1;
    if (d >= N) return;
    int q1 = 75 * half + lane;          // always < 150
    int q2 = q1 + 64;
    bool has2 = lane < 11;              // 75 chunks per half

    int start = offsets[d], cnt = counts[d];
    int s = 0, t0 = 0, t1 = 0;
    if (cnt > 0) {
        int eid = edge_list[start];
        s  = bsrc[eid];
        t0 = battr[eid * 2 + 0];
        t1 = battr[eid * 2 + 1];
    }

    const float4* slA = Wsla + atom[d * 5] * Q4;
    const float4* inr = in + (size_t)d * Q4;
    float4 acc1 = make_float4(0, 0, 0, 0), acc2 = acc1;
    acc1 = f4fma(acc1, inr[q1], f4add(slA[q1], Wsl[q1]));
    if (has2) acc2 = f4fma(acc2, inr[q2], f4add(slA[q2], Wsl[q2]));

    for (int k = 0; k < cnt; k++) {
        int ns = s, nt0 = t0, nt1 = t1;
        if (k + 1 < cnt) {
            int ne = edge_list[start + k + 1];
            ns  = bsrc[ne];
            nt0 = battr[ne * 2 + 0];
            nt1 = battr[ne * 2 + 1];
        }
        const float4* e0 = Wbt  + t0 * Q4;
        const float4* e1 = Wbai + t1 * Q4;
        const float4* sr = in + (size_t)s * Q4;
        acc1 = f4fma(acc1, sr[q1], f4add(e0[q1], e1[q1]));
        if (has2) acc2 = f4fma(acc2, sr[q2], f4add(e0[q2], e1[q2]));
        s = ns; t0 = nt0; t1 = nt1;
    }
    float4* orow = out + (size_t)d * Q4;
    orow[q1] = acc1;
    if (has2) orow[q2] = acc2;
}

// ---------------------------------------------------------------------------
// K2b: MP round 2 fused with relu + SINGLE-bf16 cast, fragment-interleaved.
// ---------------------------------------------------------------------------
__device__ __forceinline__ void frag_store4h(ushortT* __restrict__ hi,
                                             int d, int q, float4 v) {
    int kc = q >> 3, ks = (q >> 1) & 3, halfw = q & 1;
    size_t off = ((size_t)((d >> 4) * 19 + kc) * 64 + (d & 15) + 16 * ks) * 8
                 + halfw * 4;
    float vv[4] = {v.x, v.y, v.z, v.w};
    short4v h4;
#pragma unroll
    for (int j = 0; j < 4; j++)
        h4[j] = (short)bf16_rne(fmaxf(vv[j], 0.f));
    *(short4v*)(hi + off) = h4;
}

__global__ __launch_bounds__(256) void k_mp_gather_rs(
        const int* __restrict__ bsrc, const int* __restrict__ battr,
        const int* __restrict__ atom,
        const int* __restrict__ offsets, const int* __restrict__ counts,
        const int* __restrict__ edge_list,
        const float4* __restrict__ Wbt, const float4* __restrict__ Wbai,
        const float4* __restrict__ Wsla, const float4* __restrict__ Wsl,
        const float4* __restrict__ in,
        ushortT* __restrict__ hi, int N) {
    int wid  = (int)((blockIdx.x * blockDim.x + threadIdx.x) >> 6);
    int lane = threadIdx.x & 63;
    int d    = wid >> 1;
    int half = wid & 1;
    if (d >= N) return;
    int q1 = 75 * half + lane;
    int q2 = q1 + 64;
    bool has2 = lane < 11;

    int start = offsets[d], cnt = counts[d];
    int s = 0, t0 = 0, t1 = 0;
    if (cnt > 0) {
        int eid = edge_list[start];
        s  = bsrc[eid];
        t0 = battr[eid * 2 + 0];
        t1 = battr[eid * 2 + 1];
    }

    const float4* slA = Wsla + atom[d * 5] * Q4;
    const float4* inr = in + (size_t)d * Q4;
    float4 acc1 = make_float4(0, 0, 0, 0), acc2 = acc1;
    acc1 = f4fma(acc1, inr[q1], f4add(slA[q1], Wsl[q1]));
    if (has2) acc2 = f4fma(acc2, inr[q2], f4add(slA[q2], Wsl[q2]));

    for (int k = 0; k < cnt; k++) {
        int ns = s, nt0 = t0, nt1 = t1;
        if (k + 1 < cnt) {
            int ne = edge_list[start + k + 1];
            ns  = bsrc[ne];
            nt0 = battr[ne * 2 + 0];
            nt1 = battr[ne * 2 + 1];
        }
        const float4* e0 = Wbt  + t0 * Q4;
        const float4* e1 = Wbai + t1 * Q4;
        const float4* sr = in + (size_t)s * Q4;
        acc1 = f4fma(acc1, sr[q1], f4add(e0[q1], e1[q1]));
        if (has2) acc2 = f4fma(acc2, sr[q2], f4add(e0[q2], e1[q2]));
        s = ns; t0 = nt0; t1 = nt1;
    }
    frag_store4h(hi, d, q1, acc1);
    if (has2) frag_store4h(hi, d, q2, acc2);
    if (half == 0 && lane == 31) {   // zero K-pad cols 600..607 (kc=18, ks=3)
        size_t off = ((size_t)((d >> 4) * 19 + 18) * 64 + (d & 15) + 48) * 8;
        short8 z = {0, 0, 0, 0, 0, 0, 0, 0};
        *(short8*)(hi + off) = z;
    }
}

// ---------------------------------------------------------------------------
// Weight split to FRAGMENT-INTERLEAVED bf16 hi/lo (W stays exact as pair).
// ---------------------------------------------------------------------------
__global__ void k_split_w_frag(const float* __restrict__ src,
                               short8* __restrict__ dhi, short8* __restrict__ dlo,
                               int rows_in, int cb_count) {
    int idx = blockIdx.x * blockDim.x + threadIdx.x;
    int total = cb_count * 19 * 64;
    if (idx >= total) return;
    int lane = idx & 63;
    int tile = idx >> 6;
    int cb = tile / 19, kc = tile - cb * 19;
    int col = cb * 16 + (lane & 15);
    int k0  = kc * 32 + (lane >> 4) * 8;
    short8 h, l;
#pragma unroll
    for (int j = 0; j < 8; j++) {
        int k = k0 + j;
        float x = (col < rows_in && k < 600) ? src[(size_t)col * 600 + k] : 0.f;
        ushortT hh = bf16_rne(x);
        h[j] = (short)hh;
        l[j] = (short)bf16_rne(x - bf16_to_f(hh));
    }
    dhi[idx] = h;
    dlo[idx] = l;
}

// ---------------------------------------------------------------------------
// Register GEMM core (A single bf16 x W bf16-pair => 2 MFMA per frag pair):
// 128x128 block, 4 waves each own 64x64 quadrant, no LDS/barriers.
// C = A_rnd * (W_hi + W_lo); only A's bf16 rounding (2^-9 rel) remains.
// ---------------------------------------------------------------------------
struct FragSet { short8 a[4], bh[4], bl[4]; };

__device__ __forceinline__ void frag_load(FragSet& f,
        const short8* __restrict__ Af,
        const short8* __restrict__ Bfh, const short8* __restrict__ Bfl,
        int aBase, int bBase, int kc) {
    int ak = aBase + kc * 64;
    int bk = bBase + kc * 64;
#pragma unroll
    for (int i = 0; i < 4; i++) {
        f.a[i]  = Af [ak + i * 1216];   // 1216 = 19*64 short8 per row-block
        f.bh[i] = Bfh[bk + i * 1216];
        f.bl[i] = Bfl[bk + i * 1216];
    }
}

__device__ __forceinline__ void frag_mfma(const FragSet& f, f32x4 acc[4][4]) {
#pragma unroll
    for (int i = 0; i < 4; i++)
#pragma unroll
        for (int j = 0; j < 4; j++) {
            acc[i][j] = __builtin_amdgcn_mfma_f32_16x16x32_bf16(f.a[i], f.bh[j], acc[i][j], 0, 0, 0);
            acc[i][j] = __builtin_amdgcn_mfma_f32_16x16x32_bf16(f.a[i], f.bl[j], acc[i][j], 0, 0, 0);
        }
}

__device__ __forceinline__ void gemm_core_reg(
        const short8* __restrict__ Af,
        const short8* __restrict__ Bfh, const short8* __restrict__ Bfl,
        int aBase, int bBase, f32x4 acc[4][4]) {
    for (int kc = 0; kc < 19; kc++) {
        FragSet f;
        frag_load(f, Af, Bfh, Bfl, aBase, bBase, kc);
        frag_mfma(f, acc);
    }
}

// m204 bijective XCD swizzle
__device__ __forceinline__ void decode_wg(int ncb, int& rowblk, int& colblk) {
    int nwg  = gridDim.x;
    int orig = blockIdx.x;
    int q = nwg >> 3, r = nwg & 7;
    int xcd = orig & 7, rank = orig >> 3;
    int wgid = (xcd < r ? xcd * (q + 1) : r * (q + 1) + (xcd - r) * q) + rank;
    rowblk = wgid / ncb;
    colblk = wgid - rowblk * ncb;
}

// GEMM1: H = relu(A @ W1^T + b1) -> Hf (single bf16, frag-interleaved). grid Mb*5.
__global__ __launch_bounds__(256, 4) void k_gemm1r(
        const short8* __restrict__ Af,
        const short8* __restrict__ Wfh, const short8* __restrict__ Wfl,
        const float* __restrict__ b1,
        ushortT* __restrict__ Hf, int N) {
    int rowblk, colblk;
    decode_wg(5, rowblk, colblk);
    int row0 = rowblk * 128;
    int col0 = colblk * 128;
    int t = threadIdx.x, w = t >> 6, l = t & 63;
    int wr = w >> 1, wc = w & 1, fr = l & 15, fq = l >> 4;

    int aBase = (rowblk * 8 + wr * 4) * 1216 + l;
    int bBase = (colblk * 8 + wc * 4) * 1216 + l;
    f32x4 acc[4][4];
#pragma unroll
    for (int i = 0; i < 4; i++)
#pragma unroll
        for (int j = 0; j < 4; j++) acc[i][j] = f32x4{0.f, 0.f, 0.f, 0.f};
    gemm_core_reg(Af, Wfh, Wfl, aBase, bBase, acc);

#pragma unroll
    for (int i = 0; i < 4; i++) {
#pragma unroll
        for (int j = 0; j < 4; j++) {
            int col = col0 + wc * 64 + j * 16 + fr;
            float bias = (col < 600) ? b1[col] : 0.f;
#pragma unroll
            for (int r = 0; r < 4; r++) {
                int row = row0 + wr * 64 + i * 16 + fq * 4 + r;
                if (row >= N) continue;
                if (col < 600) {
                    float x = fmaxf(acc[i][j][r] + bias, 0.f);
                    Hf[frag_off(row, col)] = bf16_rne(x);
                } else if (col < KP) {
                    Hf[frag_off(row, col)] = 0;
                }
            }
        }
    }
}

// GEMM2: energy += sum_col relu(H @ W2^T + b2) * W3. grid Mb*3.
__global__ __launch_bounds__(256, 4) void k_gemm2r(
        const short8* __restrict__ Af,
        const short8* __restrict__ Wfh, const short8* __restrict__ Wfl,
        const float* __restrict__ b2, const float* __restrict__ W3,
        float* __restrict__ energy, int N) {
    __shared__ float sE[128];
    int rowblk, colblk;
    decode_wg(3, rowblk, colblk);
    int row0 = rowblk * 128;
    int col0 = colblk * 128;
    int t = threadIdx.x, w = t >> 6, l = t & 63;
    int wr = w >> 1, wc = w & 1, fr = l & 15, fq = l >> 4;

    int aBase = (rowblk * 8 + wr * 4) * 1216 + l;
    int bBase = (colblk * 8 + wc * 4) * 1216 + l;
    f32x4 acc[4][4];
#pragma unroll
    for (int i = 0; i < 4; i++)
#pragma unroll
        for (int j = 0; j < 4; j++) acc[i][j] = f32x4{0.f, 0.f, 0.f, 0.f};
    gemm_core_reg(Af, Wfh, Wfl, aBase, bBase, acc);

    if (t < 128) sE[t] = 0.f;
    __syncthreads();
#pragma unroll
    for (int i = 0; i < 4; i++) {
        float p[4] = {0.f, 0.f, 0.f, 0.f};
#pragma unroll
        for (int j = 0; j < 4; j++) {
            int col = col0 + wc * 64 + j * 16 + fr;
            if (col < 300) {
                float bias = b2[col];
                float wv   = W3[col];
#pragma unroll
                for (int r = 0; r < 4; r++)
                    p[r] += fmaxf(acc[i][j][r] + bias, 0.f) * wv;
            }
        }
#pragma unroll
        for (int r = 0; r < 4; r++) {
            float v = p[r];
            v += __shfl_xor(v, 1, 64);
            v += __shfl_xor(v, 2, 64);
            v += __shfl_xor(v, 4, 64);
            v += __shfl_xor(v, 8, 64);
            p[r] = v;
        }
        if (fr == 0) {
#pragma unroll
            for (int r = 0; r < 4; r++)
                atomicAdd(&sE[wr * 64 + i * 16 + fq * 4 + r], p[r]);
        }
    }
    __syncthreads();
    if (t < 128) {
        int row = row0 + t;
        if (row < N) atomicAdd(&energy[row], sE[t]);
    }
}

// ---------------------------------------------------------------------------
// K5: per-graph pool. batch sorted -> wave-segmented reduce, few atomics.
// ---------------------------------------------------------------------------
__global__ void k_pool(const float* __restrict__ energy, const int* __restrict__ batch,
                       float* __restrict__ dg, int N) {
    int i = blockIdx.x * blockDim.x + threadIdx.x;
    int lane = threadIdx.x & 63;
    float v = (i < N) ? energy[i] : 0.f;
    int   b = (i < N) ? batch[i]  : -1;
#pragma unroll
    for (int off = 1; off < 64; off <<= 1) {
        float vv = __shfl_down(v, off, 64);
        int   bb = __shfl_down(b, off, 64);
        if (lane + off < 64 && bb == b) v += vv;
    }
    int pb = __shfl_up(b, 1, 64);
    if (i < N && (lane == 0 || pb != b)) atomicAdd(&dg[b], v);
}

extern "C" void kernel_launch(void* const* d_in, const int* in_sizes, int n_in,
                              void* d_out, int out_size, void* d_ws, size_t ws_size,
                              hipStream_t stream) {
    const int* atom       = (const int*)d_in[0];
    const int* bond_index = (const int*)d_in[1];
    const int* bond_attr  = (const int*)d_in[2];
    const int* batch      = (const int*)d_in[3];
    const float* Wa   = (const float*)d_in[4];
    const float* Wh   = (const float*)d_in[5];
    const float* War  = (const float*)d_in[6];
    const float* Wc   = (const float*)d_in[7];
    const float* Wch  = (const float*)d_in[8];
    const float* Wbt  = (const float*)d_in[9];
    const float* Wbai = (const float*)d_in[10];
    const float* Wsla = (const float*)d_in[11];
    const float* Wsl  = (const float*)d_in[12];
    const float* W1   = (const float*)d_in[13];
    const float* b1   = (const float*)d_in[14];
    const float* W2   = (const float*)d_in[15];
    const float* b2   = (const float*)d_in[16];
    const float* W3   = (const float*)d_in[17];

    int N = in_sizes[0] / 5;   // 50000
    int E = in_sizes[1] / 2;   // 100000
    int Mb = (N + 127) / 128;  // 391
    int Npad = Mb * 128;       // 50048
    int nTiles = Npad / 16;    // 3128 row-blocks

    size_t regionBytes = (size_t)Npad * KP * 4;
    char* base = (char*)d_ws;
    float* nodeA = (float*)base;                       // region0: embed out, mp1 in
    float* nodeB = (float*)(base + regionBytes);       // region1: mp1 out, mp2 in
    short8* Af = (short8*)nodeA;                       // mp2 out (single bf16 frags)
    short8* Hf = (short8*)nodeB;                       // gemm1 out
    char* tail = base + 2 * regionBytes;
    float* energy  = (float*)tail;
    int* counts    = (int*)(energy + N);
    int* offsets   = counts + N;
    int* cursor    = offsets + N;
    int* edge_list = cursor + N;
    short8* W1fh   = (short8*)(edge_list + E);         // 40*19*64 tiles
    short8* W1fl   = W1fh + 40 * 19 * 64;
    short8* W2fh   = W1fl + 40 * 19 * 64;              // 24*19*64 tiles
    short8* W2fl   = W2fh + 24 * 19 * 64;

    const int* bsrc = bond_index;
    const int* bdst = bond_index + E;

    // CSR build (dst -> edges)
    hipMemsetAsync(counts, 0, (size_t)N * sizeof(int), stream);
    k_hist<<<(E + 255) / 256, 256, 0, stream>>>(bdst, counts, E);
    k_scan<<<1, 1024, 0, stream>>>(counts, offsets, cursor, N);
    k_scatter<<<(E + 255) / 256, 256, 0, stream>>>(bdst, cursor, edge_list, E);

    // weight splits to fragment-interleaved hi/lo
    k_split_w_frag<<<(40 * 19 * 64 + 255) / 256, 256, 0, stream>>>(W1, W1fh, W1fl, 600, 40);
    k_split_w_frag<<<(24 * 19 * 64 + 255) / 256, 256, 0, stream>>>(W2, W2fh, W2fl, 300, 24);

    // K1: node embedding -> nodeA
    {
        int total = N * Q4;
        k_node_embed<<<(total + 255) / 256, 256, 0, stream>>>(
            atom, (const float4*)Wa, (const float4*)Wh, (const float4*)War,
            (const float4*)Wc, (const float4*)Wch, (float4*)nodeA, N);
    }

    int mpblocks = (2 * N * 64 + 255) / 256;   // two waves per node
    // round 1: nodeA -> nodeB (fp32)
    k_mp_gather<<<mpblocks, 256, 0, stream>>>(bsrc, bond_attr, atom,
        offsets, counts, edge_list,
        (const float4*)Wbt, (const float4*)Wbai, (const float4*)Wsla, (const float4*)Wsl,
        (const float4*)nodeA, (float4*)nodeB, N);

    // zero A-frag pad tiles (rows N..Npad; region0 fp32 is dead now)
    {
        int firstPad = N / 16;
        size_t offB  = (size_t)firstPad * 1216 * 16;
        size_t cntB  = (size_t)(nTiles - firstPad) * 1216 * 16;
        if (cntB) hipMemsetAsync((char*)Af + offB, 0, cntB, stream);
    }

    // round 2 fused with relu + single-bf16 frag cast: nodeB -> Af
    k_mp_gather_rs<<<mpblocks, 256, 0, stream>>>(bsrc, bond_attr, atom,
        offsets, counts, edge_list,
        (const float4*)Wbt, (const float4*)Wbai, (const float4*)Wsla, (const float4*)Wsl,
        (const float4*)nodeB, (ushortT*)Af, N);

    // GEMM1: Af x W1f -> Hf (region1; nodeB dead)
    k_gemm1r<<<Mb * 5, 256, 0, stream>>>(Af, W1fh, W1fl, b1, (ushortT*)Hf, N);

    // GEMM2: Hf x W2f (+b2, W3) -> energy (atomic accumulate)
    hipMemsetAsync(energy, 0, (size_t)N * sizeof(float), stream);
    k_gemm2r<<<Mb * 3, 256, 0, stream>>>(Hf, W2fh, W2fl, b2, W3, energy, N);

    // pool
    hipMemsetAsync(d_out, 0, (size_t)out_size * sizeof(float), stream);
    k_pool<<<(N + 255) / 256, 256, 0, stream>>>(energy, batch, (float*)d_out, N);
}

// Round 12
// 392.403 us; speedup vs baseline: 1.6171x; 1.2512x over previous
//
#include <hip/hip_runtime.h>

#define EMB 600
#define Q4  150   // EMB / 4
#define KP  608   // K padded (19 * 32)

typedef unsigned short ushortT;
typedef __attribute__((ext_vector_type(8))) short short8;
typedef __attribute__((ext_vector_type(4))) short short4v;
typedef __attribute__((ext_vector_type(4))) float f32x4;

__device__ __forceinline__ float4 f4add(float4 a, float4 b) {
    return make_float4(a.x + b.x, a.y + b.y, a.z + b.z, a.w + b.w);
}
__device__ __forceinline__ float4 f4fma(float4 acc, float4 v, float4 e) {
    return make_float4(fmaf(v.x, e.x, acc.x), fmaf(v.y, e.y, acc.y),
                       fmaf(v.z, e.z, acc.z), fmaf(v.w, e.w, acc.w));
}
__device__ __forceinline__ ushortT bf16_rne(float x) {
    unsigned u = __float_as_uint(x);
    return (ushortT)((u + 0x7fffu + ((u >> 16) & 1u)) >> 16);
}
__device__ __forceinline__ float bf16_to_f(ushortT h) {
    return __uint_as_float(((unsigned)h) << 16);
}

// fragment-interleaved offset (ushort units) for element (row, col)
__device__ __forceinline__ size_t frag_off(int row, int col) {
    return ((size_t)((row >> 4) * 19 + (col >> 5)) * 64
            + (row & 15) + 16 * ((col >> 3) & 3)) * 8 + (col & 7);
}

// ---------------------------------------------------------------------------
// K1: node embedding = sum of 5 table lookups.
// ---------------------------------------------------------------------------
__global__ void k_node_embed(const int* __restrict__ atom,
                             const float4* __restrict__ Wa,
                             const float4* __restrict__ Wh,
                             const float4* __restrict__ War,
                             const float4* __restrict__ Wc,
                             const float4* __restrict__ Wch,
                             float4* __restrict__ out, int N) {
    int idx = blockIdx.x * blockDim.x + threadIdx.x;
    int total = N * Q4;
    if (idx >= total) return;
    int n = idx / Q4;
    int q = idx - n * Q4;
    const int* a = atom + n * 5;
    float4 r = Wa[a[0] * Q4 + q];
    r = f4add(r, Wh [a[1] * Q4 + q]);
    r = f4add(r, War[a[2] * Q4 + q]);
    r = f4add(r, Wc [a[3] * Q4 + q]);
    r = f4add(r, Wch[a[4] * Q4 + q]);
    out[idx] = r;
}

// ---------------------------------------------------------------------------
// CSR build: histogram -> 3-level parallel scan -> scatter
// ---------------------------------------------------------------------------
__global__ void k_hist(const int* __restrict__ bdst, int* __restrict__ counts, int E) {
    int i = blockIdx.x * blockDim.x + threadIdx.x;
    if (i < E) atomicAdd(&counts[bdst[i]], 1);
}

// L1: per-block exclusive scan of a 256-chunk; emit block total.
__global__ __launch_bounds__(256) void k_scan_l1(const int* __restrict__ counts,
                                                 int* __restrict__ offsets,
                                                 int* __restrict__ blocksums, int N) {
    __shared__ int s[256];
    int t = threadIdx.x;
    int i = blockIdx.x * 256 + t;
    int v = (i < N) ? counts[i] : 0;
    s[t] = v;
    __syncthreads();
#pragma unroll
    for (int off = 1; off < 256; off <<= 1) {
        int x = (t >= off) ? s[t - off] : 0;
        __syncthreads();
        s[t] += x;
        __syncthreads();
    }
    if (i < N) offsets[i] = s[t] - v;          // exclusive within block
    if (t == 255) blocksums[blockIdx.x] = s[255];
}

// L2: single block scans the block sums (nb <= 256).
__global__ __launch_bounds__(256) void k_scan_l2(int* __restrict__ blocksums,
                                                 int* __restrict__ blockpref, int nb) {
    __shared__ int s[256];
    int t = threadIdx.x;
    int v = (t < nb) ? blocksums[t] : 0;
    s[t] = v;
    __syncthreads();
#pragma unroll
    for (int off = 1; off < 256; off <<= 1) {
        int x = (t >= off) ? s[t - off] : 0;
        __syncthreads();
        s[t] += x;
        __syncthreads();
    }
    if (t < nb) blockpref[t] = s[t] - v;       // exclusive
}

// L3: add block prefix; emit final offsets + cursor copy.
__global__ __launch_bounds__(256) void k_scan_l3(int* __restrict__ offsets,
                                                 int* __restrict__ cursor,
                                                 const int* __restrict__ blockpref, int N) {
    int i = blockIdx.x * 256 + threadIdx.x;
    if (i < N) {
        int o = offsets[i] + blockpref[blockIdx.x];
        offsets[i] = o;
        cursor[i]  = o;
    }
}

__global__ void k_scatter(const int* __restrict__ bdst, int* __restrict__ cursor,
                          int* __restrict__ edge_list, int E) {
    int i = blockIdx.x * blockDim.x + threadIdx.x;
    if (i < E) {
        int pos = atomicAdd(&cursor[bdst[i]], 1);
        edge_list[pos] = i;
    }
}

// ---------------------------------------------------------------------------
// K2a: MP round 1 (fp32 out). TWO waves per dest node (75 float4 each).
// ---------------------------------------------------------------------------
__global__ __launch_bounds__(256) void k_mp_gather(
        const int* __restrict__ bsrc, const int* __restrict__ battr,
        const int* __restrict__ atom,
        const int* __restrict__ offsets, const int* __restrict__ counts,
        const int* __restrict__ edge_list,
        const float4* __restrict__ Wbt, const float4* __restrict__ Wbai,
        const float4* __restrict__ Wsla, const float4* __restrict__ Wsl,
        const float4* __restrict__ in, float4* __restrict__ out, int N) {
    int wid  = (int)((blockIdx.x * blockDim.x + threadIdx.x) >> 6);
    int lane = threadIdx.x & 63;
    int d    = wid >> 1;
    int half = wid & 1;
    if (d >= N) return;
    int q1 = 75 * half + lane;
    int q2 = q1 + 64;
    bool has2 = lane < 11;

    int start = offsets[d], cnt = counts[d];
    int s = 0, t0 = 0, t1 = 0;
    if (cnt > 0) {
        int eid = edge_list[start];
        s  = bsrc[eid];
        t0 = battr[eid * 2 + 0];
        t1 = battr[eid * 2 + 1];
    }

    const float4* slA = Wsla + atom[d * 5] * Q4;
    const float4* inr = in + (size_t)d * Q4;
    float4 acc1 = make_float4(0, 0, 0, 0), acc2 = acc1;
    acc1 = f4fma(acc1, inr[q1], f4add(slA[q1], Wsl[q1]));
    if (has2) acc2 = f4fma(acc2, inr[q2], f4add(slA[q2], Wsl[q2]));

    for (int k = 0; k < cnt; k++) {
        int ns = s, nt0 = t0, nt1 = t1;
        if (k + 1 < cnt) {
            int ne = edge_list[start + k + 1];
            ns  = bsrc[ne];
            nt0 = battr[ne * 2 + 0];
            nt1 = battr[ne * 2 + 1];
        }
        const float4* e0 = Wbt  + t0 * Q4;
        const float4* e1 = Wbai + t1 * Q4;
        const float4* sr = in + (size_t)s * Q4;
        acc1 = f4fma(acc1, sr[q1], f4add(e0[q1], e1[q1]));
        if (has2) acc2 = f4fma(acc2, sr[q2], f4add(e0[q2], e1[q2]));
        s = ns; t0 = nt0; t1 = nt1;
    }
    float4* orow = out + (size_t)d * Q4;
    orow[q1] = acc1;
    if (has2) orow[q2] = acc2;
}

// ---------------------------------------------------------------------------
// K2b: MP round 2 fused with relu + SINGLE-bf16 cast, fragment-interleaved.
// ---------------------------------------------------------------------------
__device__ __forceinline__ void frag_store4h(ushortT* __restrict__ hi,
                                             int d, int q, float4 v) {
    int kc = q >> 3, ks = (q >> 1) & 3, halfw = q & 1;
    size_t off = ((size_t)((d >> 4) * 19 + kc) * 64 + (d & 15) + 16 * ks) * 8
                 + halfw * 4;
    float vv[4] = {v.x, v.y, v.z, v.w};
    short4v h4;
#pragma unroll
    for (int j = 0; j < 4; j++)
        h4[j] = (short)bf16_rne(fmaxf(vv[j], 0.f));
    *(short4v*)(hi + off) = h4;
}

__global__ __launch_bounds__(256) void k_mp_gather_rs(
        const int* __restrict__ bsrc, const int* __restrict__ battr,
        const int* __restrict__ atom,
        const int* __restrict__ offsets, const int* __restrict__ counts,
        const int* __restrict__ edge_list,
        const float4* __restrict__ Wbt, const float4* __restrict__ Wbai,
        const float4* __restrict__ Wsla, const float4* __restrict__ Wsl,
        const float4* __restrict__ in,
        ushortT* __restrict__ hi, int N) {
    int wid  = (int)((blockIdx.x * blockDim.x + threadIdx.x) >> 6);
    int lane = threadIdx.x & 63;
    int d    = wid >> 1;
    int half = wid & 1;
    if (d >= N) return;
    int q1 = 75 * half + lane;
    int q2 = q1 + 64;
    bool has2 = lane < 11;

    int start = offsets[d], cnt = counts[d];
    int s = 0, t0 = 0, t1 = 0;
    if (cnt > 0) {
        int eid = edge_list[start];
        s  = bsrc[eid];
        t0 = battr[eid * 2 + 0];
        t1 = battr[eid * 2 + 1];
    }

    const float4* slA = Wsla + atom[d * 5] * Q4;
    const float4* inr = in + (size_t)d * Q4;
    float4 acc1 = make_float4(0, 0, 0, 0), acc2 = acc1;
    acc1 = f4fma(acc1, inr[q1], f4add(slA[q1], Wsl[q1]));
    if (has2) acc2 = f4fma(acc2, inr[q2], f4add(slA[q2], Wsl[q2]));

    for (int k = 0; k < cnt; k++) {
        int ns = s, nt0 = t0, nt1 = t1;
        if (k + 1 < cnt) {
            int ne = edge_list[start + k + 1];
            ns  = bsrc[ne];
            nt0 = battr[ne * 2 + 0];
            nt1 = battr[ne * 2 + 1];
        }
        const float4* e0 = Wbt  + t0 * Q4;
        const float4* e1 = Wbai + t1 * Q4;
        const float4* sr = in + (size_t)s * Q4;
        acc1 = f4fma(acc1, sr[q1], f4add(e0[q1], e1[q1]));
        if (has2) acc2 = f4fma(acc2, sr[q2], f4add(e0[q2], e1[q2]));
        s = ns; t0 = nt0; t1 = nt1;
    }
    frag_store4h(hi, d, q1, acc1);
    if (has2) frag_store4h(hi, d, q2, acc2);
    if (half == 0 && lane == 31) {   // zero K-pad cols 600..607 (kc=18, ks=3)
        size_t off = ((size_t)((d >> 4) * 19 + 18) * 64 + (d & 15) + 48) * 8;
        short8 z = {0, 0, 0, 0, 0, 0, 0, 0};
        *(short8*)(hi + off) = z;
    }
}

// ---------------------------------------------------------------------------
// Weight split to FRAGMENT-INTERLEAVED bf16 hi/lo (W stays exact as pair).
// ---------------------------------------------------------------------------
__global__ void k_split_w_frag(const float* __restrict__ src,
                               short8* __restrict__ dhi, short8* __restrict__ dlo,
                               int rows_in, int cb_count) {
    int idx = blockIdx.x * blockDim.x + threadIdx.x;
    int total = cb_count * 19 * 64;
    if (idx >= total) return;
    int lane = idx & 63;
    int tile = idx >> 6;
    int cb = tile / 19, kc = tile - cb * 19;
    int col = cb * 16 + (lane & 15);
    int k0  = kc * 32 + (lane >> 4) * 8;
    short8 h, l;
#pragma unroll
    for (int j = 0; j < 8; j++) {
        int k = k0 + j;
        float x = (col < rows_in && k < 600) ? src[(size_t)col * 600 + k] : 0.f;
        ushortT hh = bf16_rne(x);
        h[j] = (short)hh;
        l[j] = (short)bf16_rne(x - bf16_to_f(hh));
    }
    dhi[idx] = h;
    dlo[idx] = l;
}

// ---------------------------------------------------------------------------
// Register GEMM core (A single bf16 x W bf16-pair): 128x128 block, 4 waves,
// no LDS/barriers.
// ---------------------------------------------------------------------------
struct FragSet { short8 a[4], bh[4], bl[4]; };

__device__ __forceinline__ void frag_load(FragSet& f,
        const short8* __restrict__ Af,
        const short8* __restrict__ Bfh, const short8* __restrict__ Bfl,
        int aBase, int bBase, int kc) {
    int ak = aBase + kc * 64;
    int bk = bBase + kc * 64;
#pragma unroll
    for (int i = 0; i < 4; i++) {
        f.a[i]  = Af [ak + i * 1216];   // 1216 = 19*64 short8 per row-block
        f.bh[i] = Bfh[bk + i * 1216];
        f.bl[i] = Bfl[bk + i * 1216];
    }
}

__device__ __forceinline__ void frag_mfma(const FragSet& f, f32x4 acc[4][4]) {
#pragma unroll
    for (int i = 0; i < 4; i++)
#pragma unroll
        for (int j = 0; j < 4; j++) {
            acc[i][j] = __builtin_amdgcn_mfma_f32_16x16x32_bf16(f.a[i], f.bh[j], acc[i][j], 0, 0, 0);
            acc[i][j] = __builtin_amdgcn_mfma_f32_16x16x32_bf16(f.a[i], f.bl[j], acc[i][j], 0, 0, 0);
        }
}

__device__ __forceinline__ void gemm_core_reg(
        const short8* __restrict__ Af,
        const short8* __restrict__ Bfh, const short8* __restrict__ Bfl,
        int aBase, int bBase, f32x4 acc[4][4]) {
    for (int kc = 0; kc < 19; kc++) {
        FragSet f;
        frag_load(f, Af, Bfh, Bfl, aBase, bBase, kc);
        frag_mfma(f, acc);
    }
}

// m204 bijective XCD swizzle
__device__ __forceinline__ void decode_wg(int ncb, int& rowblk, int& colblk) {
    int nwg  = gridDim.x;
    int orig = blockIdx.x;
    int q = nwg >> 3, r = nwg & 7;
    int xcd = orig & 7, rank = orig >> 3;
    int wgid = (xcd < r ? xcd * (q + 1) : r * (q + 1) + (xcd - r) * q) + rank;
    rowblk = wgid / ncb;
    colblk = wgid - rowblk * ncb;
}

// GEMM1: H = relu(A @ W1^T + b1) -> Hf (single bf16, frag-interleaved). grid Mb*5.
__global__ __launch_bounds__(256, 4) void k_gemm1r(
        const short8* __restrict__ Af,
        const short8* __restrict__ Wfh, const short8* __restrict__ Wfl,
        const float* __restrict__ b1,
        ushortT* __restrict__ Hf, int N) {
    int rowblk, colblk;
    decode_wg(5, rowblk, colblk);
    int row0 = rowblk * 128;
    int col0 = colblk * 128;
    int t = threadIdx.x, w = t >> 6, l = t & 63;
    int wr = w >> 1, wc = w & 1, fr = l & 15, fq = l >> 4;

    int aBase = (rowblk * 8 + wr * 4) * 1216 + l;
    int bBase = (colblk * 8 + wc * 4) * 1216 + l;
    f32x4 acc[4][4];
#pragma unroll
    for (int i = 0; i < 4; i++)
#pragma unroll
        for (int j = 0; j < 4; j++) acc[i][j] = f32x4{0.f, 0.f, 0.f, 0.f};
    gemm_core_reg(Af, Wfh, Wfl, aBase, bBase, acc);

#pragma unroll
    for (int i = 0; i < 4; i++) {
#pragma unroll
        for (int j = 0; j < 4; j++) {
            int col = col0 + wc * 64 + j * 16 + fr;
            float bias = (col < 600) ? b1[col] : 0.f;
#pragma unroll
            for (int r = 0; r < 4; r++) {
                int row = row0 + wr * 64 + i * 16 + fq * 4 + r;
                if (row >= N) continue;
                if (col < 600) {
                    float x = fmaxf(acc[i][j][r] + bias, 0.f);
                    Hf[frag_off(row, col)] = bf16_rne(x);
                } else if (col < KP) {
                    Hf[frag_off(row, col)] = 0;
                }
            }
        }
    }
}

// GEMM2: energy += sum_col relu(H @ W2^T + b2) * W3. grid Mb*3.
__global__ __launch_bounds__(256, 4) void k_gemm2r(
        const short8* __restrict__ Af,
        const short8* __restrict__ Wfh, const short8* __restrict__ Wfl,
        const float* __restrict__ b2, const float* __restrict__ W3,
        float* __restrict__ energy, int N) {
    __shared__ float sE[128];
    int rowblk, colblk;
    decode_wg(3, rowblk, colblk);
    int row0 = rowblk * 128;
    int col0 = colblk * 128;
    int t = threadIdx.x, w = t >> 6, l = t & 63;
    int wr = w >> 1, wc = w & 1, fr = l & 15, fq = l >> 4;

    int aBase = (rowblk * 8 + wr * 4) * 1216 + l;
    int bBase = (colblk * 8 + wc * 4) * 1216 + l;
    f32x4 acc[4][4];
#pragma unroll
    for (int i = 0; i < 4; i++)
#pragma unroll
        for (int j = 0; j < 4; j++) acc[i][j] = f32x4{0.f, 0.f, 0.f, 0.f};
    gemm_core_reg(Af, Wfh, Wfl, aBase, bBase, acc);

    if (t < 128) sE[t] = 0.f;
    __syncthreads();
#pragma unroll
    for (int i = 0; i < 4; i++) {
        float p[4] = {0.f, 0.f, 0.f, 0.f};
#pragma unroll
        for (int j = 0; j < 4; j++) {
            int col = col0 + wc * 64 + j * 16 + fr;
            if (col < 300) {
                float bias = b2[col];
                float wv   = W3[col];
#pragma unroll
                for (int r = 0; r < 4; r++)
                    p[r] += fmaxf(acc[i][j][r] + bias, 0.f) * wv;
            }
        }
#pragma unroll
        for (int r = 0; r < 4; r++) {
            float v = p[r];
            v += __shfl_xor(v, 1, 64);
            v += __shfl_xor(v, 2, 64);
            v += __shfl_xor(v, 4, 64);
            v += __shfl_xor(v, 8, 64);
            p[r] = v;
        }
        if (fr == 0) {
#pragma unroll
            for (int r = 0; r < 4; r++)
                atomicAdd(&sE[wr * 64 + i * 16 + fq * 4 + r], p[r]);
        }
    }
    __syncthreads();
    if (t < 128) {
        int row = row0 + t;
        if (row < N) atomicAdd(&energy[row], sE[t]);
    }
}

// ---------------------------------------------------------------------------
// K5: per-graph pool. batch sorted -> wave-segmented reduce, few atomics.
// ---------------------------------------------------------------------------
__global__ void k_pool(const float* __restrict__ energy, const int* __restrict__ batch,
                       float* __restrict__ dg, int N) {
    int i = blockIdx.x * blockDim.x + threadIdx.x;
    int lane = threadIdx.x & 63;
    float v = (i < N) ? energy[i] : 0.f;
    int   b = (i < N) ? batch[i]  : -1;
#pragma unroll
    for (int off = 1; off < 64; off <<= 1) {
        float vv = __shfl_down(v, off, 64);
        int   bb = __shfl_down(b, off, 64);
        if (lane + off < 64 && bb == b) v += vv;
    }
    int pb = __shfl_up(b, 1, 64);
    if (i < N && (lane == 0 || pb != b)) atomicAdd(&dg[b], v);
}

extern "C" void kernel_launch(void* const* d_in, const int* in_sizes, int n_in,
                              void* d_out, int out_size, void* d_ws, size_t ws_size,
                              hipStream_t stream) {
    const int* atom       = (const int*)d_in[0];
    const int* bond_index = (const int*)d_in[1];
    const int* bond_attr  = (const int*)d_in[2];
    const int* batch      = (const int*)d_in[3];
    const float* Wa   = (const float*)d_in[4];
    const float* Wh   = (const float*)d_in[5];
    const float* War  = (const float*)d_in[6];
    const float* Wc   = (const float*)d_in[7];
    const float* Wch  = (const float*)d_in[8];
    const float* Wbt  = (const float*)d_in[9];
    const float* Wbai = (const float*)d_in[10];
    const float* Wsla = (const float*)d_in[11];
    const float* Wsl  = (const float*)d_in[12];
    const float* W1   = (const float*)d_in[13];
    const float* b1   = (const float*)d_in[14];
    const float* W2   = (const float*)d_in[15];
    const float* b2   = (const float*)d_in[16];
    const float* W3   = (const float*)d_in[17];

    int N = in_sizes[0] / 5;   // 50000
    int E = in_sizes[1] / 2;   // 100000
    int Mb = (N + 127) / 128;  // 391
    int Npad = Mb * 128;       // 50048
    int nTiles = Npad / 16;    // 3128 row-blocks
    int nb = (N + 255) / 256;  // 196 scan blocks

    size_t regionBytes = (size_t)Npad * KP * 4;
    char* base = (char*)d_ws;
    float* nodeA = (float*)base;                       // region0: embed out, mp1 in
    float* nodeB = (float*)(base + regionBytes);       // region1: mp1 out, mp2 in
    short8* Af = (short8*)nodeA;                       // mp2 out (single bf16 frags)
    short8* Hf = (short8*)nodeB;                       // gemm1 out
    char* tail = base + 2 * regionBytes;
    float* energy  = (float*)tail;
    int* counts    = (int*)(energy + N);
    int* offsets   = counts + N;
    int* cursor    = offsets + N;
    int* edge_list = cursor + N;
    short8* W1fh   = (short8*)(edge_list + E);         // 40*19*64 tiles
    short8* W1fl   = W1fh + 40 * 19 * 64;
    short8* W2fh   = W1fl + 40 * 19 * 64;              // 24*19*64 tiles
    short8* W2fl   = W2fh + 24 * 19 * 64;
    int* blocksums = (int*)(W2fl + 24 * 19 * 64);
    int* blockpref = blocksums + 256;

    const int* bsrc = bond_index;
    const int* bdst = bond_index + E;

    // CSR build (dst -> edges)
    hipMemsetAsync(counts, 0, (size_t)N * sizeof(int), stream);
    k_hist<<<(E + 255) / 256, 256, 0, stream>>>(bdst, counts, E);
    k_scan_l1<<<nb, 256, 0, stream>>>(counts, offsets, blocksums, N);
    k_scan_l2<<<1, 256, 0, stream>>>(blocksums, blockpref, nb);
    k_scan_l3<<<nb, 256, 0, stream>>>(offsets, cursor, blockpref, N);
    k_scatter<<<(E + 255) / 256, 256, 0, stream>>>(bdst, cursor, edge_list, E);

    // weight splits to fragment-interleaved hi/lo
    k_split_w_frag<<<(40 * 19 * 64 + 255) / 256, 256, 0, stream>>>(W1, W1fh, W1fl, 600, 40);
    k_split_w_frag<<<(24 * 19 * 64 + 255) / 256, 256, 0, stream>>>(W2, W2fh, W2fl, 300, 24);

    // K1: node embedding -> nodeA
    {
        int total = N * Q4;
        k_node_embed<<<(total + 255) / 256, 256, 0, stream>>>(
            atom, (const float4*)Wa, (const float4*)Wh, (const float4*)War,
            (const float4*)Wc, (const float4*)Wch, (float4*)nodeA, N);
    }

    int mpblocks = (2 * N * 64 + 255) / 256;   // two waves per node
    // round 1: nodeA -> nodeB (fp32)
    k_mp_gather<<<mpblocks, 256, 0, stream>>>(bsrc, bond_attr, atom,
        offsets, counts, edge_list,
        (const float4*)Wbt, (const float4*)Wbai, (const float4*)Wsla, (const float4*)Wsl,
        (const float4*)nodeA, (float4*)nodeB, N);

    // zero A-frag pad tiles (rows N..Npad; region0 fp32 is dead now)
    {
        int firstPad = N / 16;
        size_t offB  = (size_t)firstPad * 1216 * 16;
        size_t cntB  = (size_t)(nTiles - firstPad) * 1216 * 16;
        if (cntB) hipMemsetAsync((char*)Af + offB, 0, cntB, stream);
    }

    // round 2 fused with relu + single-bf16 frag cast: nodeB -> Af
    k_mp_gather_rs<<<mpblocks, 256, 0, stream>>>(bsrc, bond_attr, atom,
        offsets, counts, edge_list,
        (const float4*)Wbt, (const float4*)Wbai, (const float4*)Wsla, (const float4*)Wsl,
        (const float4*)nodeB, (ushortT*)Af, N);

    // GEMM1: Af x W1f -> Hf (region1; nodeB dead)
    k_gemm1r<<<Mb * 5, 256, 0, stream>>>(Af, W1fh, W1fl, b1, (ushortT*)Hf, N);

    // GEMM2: Hf x W2f (+b2, W3) -> energy (atomic accumulate)
    hipMemsetAsync(energy, 0, (size_t)N * sizeof(float), stream);
    k_gemm2r<<<Mb * 3, 256, 0, stream>>>(Hf, W2fh, W2fl, b2, W3, energy, N);

    // pool
    hipMemsetAsync(d_out, 0, (size_t)out_size * sizeof(float), stream);
    k_pool<<<(N + 255) / 256, 256, 0, stream>>>(energy, batch, (float*)d_out, N);
}

// Round 13
// 348.898 us; speedup vs baseline: 1.8188x; 1.1247x over previous
//
#include <hip/hip_runtime.h>

#define EMB 600
#define Q4  150   // EMB / 4
#define KP  608   // K padded (19 * 32)

typedef unsigned short ushortT;
typedef __attribute__((ext_vector_type(8))) short short8;
typedef __attribute__((ext_vector_type(4))) short short4v;
typedef __attribute__((ext_vector_type(4))) float f32x4;

__device__ __forceinline__ float4 f4add(float4 a, float4 b) {
    return make_float4(a.x + b.x, a.y + b.y, a.z + b.z, a.w + b.w);
}
__device__ __forceinline__ float4 f4fma(float4 acc, float4 v, float4 e) {
    return make_float4(fmaf(v.x, e.x, acc.x), fmaf(v.y, e.y, acc.y),
                       fmaf(v.z, e.z, acc.z), fmaf(v.w, e.w, acc.w));
}
__device__ __forceinline__ ushortT bf16_rne(float x) {
    unsigned u = __float_as_uint(x);
    return (ushortT)((u + 0x7fffu + ((u >> 16) & 1u)) >> 16);
}
__device__ __forceinline__ float bf16_to_f(ushortT h) {
    return __uint_as_float(((unsigned)h) << 16);
}
__device__ __forceinline__ short4v f4_to_bf4(float4 v) {
    short4v r;
    r[0] = (short)bf16_rne(v.x);
    r[1] = (short)bf16_rne(v.y);
    r[2] = (short)bf16_rne(v.z);
    r[3] = (short)bf16_rne(v.w);
    return r;
}
__device__ __forceinline__ float4 bf4_to_f4(short4v h) {
    return make_float4(bf16_to_f((ushortT)h[0]), bf16_to_f((ushortT)h[1]),
                       bf16_to_f((ushortT)h[2]), bf16_to_f((ushortT)h[3]));
}

// fragment-interleaved offset (ushort units) for element (row, col)
__device__ __forceinline__ size_t frag_off(int row, int col) {
    return ((size_t)((row >> 4) * 19 + (col >> 5)) * 64
            + (row & 15) + 16 * ((col >> 3) & 3)) * 8 + (col & 7);
}

// ---------------------------------------------------------------------------
// K1: node embedding = sum of 5 table lookups (fp32 out).
// ---------------------------------------------------------------------------
__global__ void k_node_embed(const int* __restrict__ atom,
                             const float4* __restrict__ Wa,
                             const float4* __restrict__ Wh,
                             const float4* __restrict__ War,
                             const float4* __restrict__ Wc,
                             const float4* __restrict__ Wch,
                             float4* __restrict__ out, int N) {
    int idx = blockIdx.x * blockDim.x + threadIdx.x;
    int total = N * Q4;
    if (idx >= total) return;
    int n = idx / Q4;
    int q = idx - n * Q4;
    const int* a = atom + n * 5;
    float4 r = Wa[a[0] * Q4 + q];
    r = f4add(r, Wh [a[1] * Q4 + q]);
    r = f4add(r, War[a[2] * Q4 + q]);
    r = f4add(r, Wc [a[3] * Q4 + q]);
    r = f4add(r, Wch[a[4] * Q4 + q]);
    out[idx] = r;
}

// ---------------------------------------------------------------------------
// CSR build: histogram -> 3-level parallel scan -> scatter
// ---------------------------------------------------------------------------
__global__ void k_hist(const int* __restrict__ bdst, int* __restrict__ counts, int E) {
    int i = blockIdx.x * blockDim.x + threadIdx.x;
    if (i < E) atomicAdd(&counts[bdst[i]], 1);
}

__global__ __launch_bounds__(256) void k_scan_l1(const int* __restrict__ counts,
                                                 int* __restrict__ offsets,
                                                 int* __restrict__ blocksums, int N) {
    __shared__ int s[256];
    int t = threadIdx.x;
    int i = blockIdx.x * 256 + t;
    int v = (i < N) ? counts[i] : 0;
    s[t] = v;
    __syncthreads();
#pragma unroll
    for (int off = 1; off < 256; off <<= 1) {
        int x = (t >= off) ? s[t - off] : 0;
        __syncthreads();
        s[t] += x;
        __syncthreads();
    }
    if (i < N) offsets[i] = s[t] - v;
    if (t == 255) blocksums[blockIdx.x] = s[255];
}

__global__ __launch_bounds__(256) void k_scan_l2(int* __restrict__ blocksums,
                                                 int* __restrict__ blockpref, int nb) {
    __shared__ int s[256];
    int t = threadIdx.x;
    int v = (t < nb) ? blocksums[t] : 0;
    s[t] = v;
    __syncthreads();
#pragma unroll
    for (int off = 1; off < 256; off <<= 1) {
        int x = (t >= off) ? s[t - off] : 0;
        __syncthreads();
        s[t] += x;
        __syncthreads();
    }
    if (t < nb) blockpref[t] = s[t] - v;
}

__global__ __launch_bounds__(256) void k_scan_l3(int* __restrict__ offsets,
                                                 int* __restrict__ cursor,
                                                 const int* __restrict__ blockpref, int N) {
    int i = blockIdx.x * 256 + threadIdx.x;
    if (i < N) {
        int o = offsets[i] + blockpref[blockIdx.x];
        offsets[i] = o;
        cursor[i]  = o;
    }
}

__global__ void k_scatter(const int* __restrict__ bdst, int* __restrict__ cursor,
                          int* __restrict__ edge_list, int E) {
    int i = blockIdx.x * blockDim.x + threadIdx.x;
    if (i < E) {
        int pos = atomicAdd(&cursor[bdst[i]], 1);
        edge_list[pos] = i;
    }
}

// ---------------------------------------------------------------------------
// K2a: MP round 1. fp32 in (nodeA), SINGLE-bf16 row-major out [N][600].
// TWO waves per dest node (75 chunks each).
// ---------------------------------------------------------------------------
__global__ __launch_bounds__(256) void k_mp_gather_b(
        const int* __restrict__ bsrc, const int* __restrict__ battr,
        const int* __restrict__ atom,
        const int* __restrict__ offsets, const int* __restrict__ counts,
        const int* __restrict__ edge_list,
        const float4* __restrict__ Wbt, const float4* __restrict__ Wbai,
        const float4* __restrict__ Wsla, const float4* __restrict__ Wsl,
        const float4* __restrict__ in, ushortT* __restrict__ out, int N) {
    int wid  = (int)((blockIdx.x * blockDim.x + threadIdx.x) >> 6);
    int lane = threadIdx.x & 63;
    int d    = wid >> 1;
    int half = wid & 1;
    if (d >= N) return;
    int q1 = 75 * half + lane;
    int q2 = q1 + 64;
    bool has2 = lane < 11;

    int start = offsets[d], cnt = counts[d];
    int s = 0, t0 = 0, t1 = 0;
    if (cnt > 0) {
        int eid = edge_list[start];
        s  = bsrc[eid];
        t0 = battr[eid * 2 + 0];
        t1 = battr[eid * 2 + 1];
    }

    const float4* slA = Wsla + atom[d * 5] * Q4;
    const float4* inr = in + (size_t)d * Q4;
    float4 acc1 = make_float4(0, 0, 0, 0), acc2 = acc1;
    acc1 = f4fma(acc1, inr[q1], f4add(slA[q1], Wsl[q1]));
    if (has2) acc2 = f4fma(acc2, inr[q2], f4add(slA[q2], Wsl[q2]));

    for (int k = 0; k < cnt; k++) {
        int ns = s, nt0 = t0, nt1 = t1;
        if (k + 1 < cnt) {
            int ne = edge_list[start + k + 1];
            ns  = bsrc[ne];
            nt0 = battr[ne * 2 + 0];
            nt1 = battr[ne * 2 + 1];
        }
        const float4* e0 = Wbt  + t0 * Q4;
        const float4* e1 = Wbai + t1 * Q4;
        const float4* sr = in + (size_t)s * Q4;
        acc1 = f4fma(acc1, sr[q1], f4add(e0[q1], e1[q1]));
        if (has2) acc2 = f4fma(acc2, sr[q2], f4add(e0[q2], e1[q2]));
        s = ns; t0 = nt0; t1 = nt1;
    }
    ushortT* orow = out + (size_t)d * EMB;
    *(short4v*)(orow + q1 * 4) = f4_to_bf4(acc1);
    if (has2) *(short4v*)(orow + q2 * 4) = f4_to_bf4(acc2);
}

// ---------------------------------------------------------------------------
// K2b: MP round 2. bf16 row-major in, relu + single-bf16 frag-interleaved out.
// ---------------------------------------------------------------------------
__device__ __forceinline__ void frag_store4h(ushortT* __restrict__ hi,
                                             int d, int q, float4 v) {
    int kc = q >> 3, ks = (q >> 1) & 3, halfw = q & 1;
    size_t off = ((size_t)((d >> 4) * 19 + kc) * 64 + (d & 15) + 16 * ks) * 8
                 + halfw * 4;
    float vv[4] = {v.x, v.y, v.z, v.w};
    short4v h4;
#pragma unroll
    for (int j = 0; j < 4; j++)
        h4[j] = (short)bf16_rne(fmaxf(vv[j], 0.f));
    *(short4v*)(hi + off) = h4;
}

__global__ __launch_bounds__(256) void k_mp_gather_rs(
        const int* __restrict__ bsrc, const int* __restrict__ battr,
        const int* __restrict__ atom,
        const int* __restrict__ offsets, const int* __restrict__ counts,
        const int* __restrict__ edge_list,
        const float4* __restrict__ Wbt, const float4* __restrict__ Wbai,
        const float4* __restrict__ Wsla, const float4* __restrict__ Wsl,
        const ushortT* __restrict__ in,
        ushortT* __restrict__ hi, int N) {
    int wid  = (int)((blockIdx.x * blockDim.x + threadIdx.x) >> 6);
    int lane = threadIdx.x & 63;
    int d    = wid >> 1;
    int half = wid & 1;
    if (d >= N) return;
    int q1 = 75 * half + lane;
    int q2 = q1 + 64;
    bool has2 = lane < 11;

    int start = offsets[d], cnt = counts[d];
    int s = 0, t0 = 0, t1 = 0;
    if (cnt > 0) {
        int eid = edge_list[start];
        s  = bsrc[eid];
        t0 = battr[eid * 2 + 0];
        t1 = battr[eid * 2 + 1];
    }

    const float4* slA = Wsla + atom[d * 5] * Q4;
    const ushortT* inr = in + (size_t)d * EMB;
    float4 acc1 = make_float4(0, 0, 0, 0), acc2 = acc1;
    acc1 = f4fma(acc1, bf4_to_f4(*(const short4v*)(inr + q1 * 4)),
                 f4add(slA[q1], Wsl[q1]));
    if (has2) acc2 = f4fma(acc2, bf4_to_f4(*(const short4v*)(inr + q2 * 4)),
                           f4add(slA[q2], Wsl[q2]));

    for (int k = 0; k < cnt; k++) {
        int ns = s, nt0 = t0, nt1 = t1;
        if (k + 1 < cnt) {
            int ne = edge_list[start + k + 1];
            ns  = bsrc[ne];
            nt0 = battr[ne * 2 + 0];
            nt1 = battr[ne * 2 + 1];
        }
        const float4* e0 = Wbt  + t0 * Q4;
        const float4* e1 = Wbai + t1 * Q4;
        const ushortT* sr = in + (size_t)s * EMB;
        acc1 = f4fma(acc1, bf4_to_f4(*(const short4v*)(sr + q1 * 4)),
                     f4add(e0[q1], e1[q1]));
        if (has2) acc2 = f4fma(acc2, bf4_to_f4(*(const short4v*)(sr + q2 * 4)),
                               f4add(e0[q2], e1[q2]));
        s = ns; t0 = nt0; t1 = nt1;
    }
    frag_store4h(hi, d, q1, acc1);
    if (has2) frag_store4h(hi, d, q2, acc2);
    if (half == 0 && lane == 31) {   // zero K-pad cols 600..607 (kc=18, ks=3)
        size_t off = ((size_t)((d >> 4) * 19 + 18) * 64 + (d & 15) + 48) * 8;
        short8 z = {0, 0, 0, 0, 0, 0, 0, 0};
        *(short8*)(hi + off) = z;
    }
}

// ---------------------------------------------------------------------------
// Weight split to FRAGMENT-INTERLEAVED single bf16.
// ---------------------------------------------------------------------------
__global__ void k_split_w_frag(const float* __restrict__ src,
                               short8* __restrict__ dst,
                               int rows_in, int cb_count) {
    int idx = blockIdx.x * blockDim.x + threadIdx.x;
    int total = cb_count * 19 * 64;
    if (idx >= total) return;
    int lane = idx & 63;
    int tile = idx >> 6;
    int cb = tile / 19, kc = tile - cb * 19;
    int col = cb * 16 + (lane & 15);
    int k0  = kc * 32 + (lane >> 4) * 8;
    short8 h;
#pragma unroll
    for (int j = 0; j < 8; j++) {
        int k = k0 + j;
        float x = (col < rows_in && k < 600) ? src[(size_t)col * 600 + k] : 0.f;
        h[j] = (short)bf16_rne(x);
    }
    dst[idx] = h;
}

// ---------------------------------------------------------------------------
// Register GEMM core (single bf16 x single bf16): 128x128 block, 4 waves,
// no LDS/barriers. 16 MFMA + 8 loads per kc per wave.
// ---------------------------------------------------------------------------
struct FragSet { short8 a[4], b[4]; };

__device__ __forceinline__ void frag_load(FragSet& f,
        const short8* __restrict__ Af, const short8* __restrict__ Bf,
        int aBase, int bBase, int kc) {
    int ak = aBase + kc * 64;
    int bk = bBase + kc * 64;
#pragma unroll
    for (int i = 0; i < 4; i++) {
        f.a[i] = Af[ak + i * 1216];   // 1216 = 19*64 short8 per row-block
        f.b[i] = Bf[bk + i * 1216];
    }
}

__device__ __forceinline__ void frag_mfma(const FragSet& f, f32x4 acc[4][4]) {
#pragma unroll
    for (int i = 0; i < 4; i++)
#pragma unroll
        for (int j = 0; j < 4; j++)
            acc[i][j] = __builtin_amdgcn_mfma_f32_16x16x32_bf16(f.a[i], f.b[j], acc[i][j], 0, 0, 0);
}

__device__ __forceinline__ void gemm_core_reg(
        const short8* __restrict__ Af, const short8* __restrict__ Bf,
        int aBase, int bBase, f32x4 acc[4][4]) {
    for (int kc = 0; kc < 19; kc++) {
        FragSet f;
        frag_load(f, Af, Bf, aBase, bBase, kc);
        frag_mfma(f, acc);
    }
}

// m204 bijective XCD swizzle
__device__ __forceinline__ void decode_wg(int ncb, int& rowblk, int& colblk) {
    int nwg  = gridDim.x;
    int orig = blockIdx.x;
    int q = nwg >> 3, r = nwg & 7;
    int xcd = orig & 7, rank = orig >> 3;
    int wgid = (xcd < r ? xcd * (q + 1) : r * (q + 1) + (xcd - r) * q) + rank;
    rowblk = wgid / ncb;
    colblk = wgid - rowblk * ncb;
}

// GEMM1: H = relu(A @ W1^T + b1) -> Hf (single bf16, frag-interleaved). grid Mb*5.
__global__ __launch_bounds__(256, 4) void k_gemm1r(
        const short8* __restrict__ Af, const short8* __restrict__ Wf,
        const float* __restrict__ b1,
        ushortT* __restrict__ Hf, int N) {
    int rowblk, colblk;
    decode_wg(5, rowblk, colblk);
    int row0 = rowblk * 128;
    int col0 = colblk * 128;
    int t = threadIdx.x, w = t >> 6, l = t & 63;
    int wr = w >> 1, wc = w & 1, fr = l & 15, fq = l >> 4;

    int aBase = (rowblk * 8 + wr * 4) * 1216 + l;
    int bBase = (colblk * 8 + wc * 4) * 1216 + l;
    f32x4 acc[4][4];
#pragma unroll
    for (int i = 0; i < 4; i++)
#pragma unroll
        for (int j = 0; j < 4; j++) acc[i][j] = f32x4{0.f, 0.f, 0.f, 0.f};
    gemm_core_reg(Af, Wf, aBase, bBase, acc);

#pragma unroll
    for (int i = 0; i < 4; i++) {
#pragma unroll
        for (int j = 0; j < 4; j++) {
            int col = col0 + wc * 64 + j * 16 + fr;
            float bias = (col < 600) ? b1[col] : 0.f;
#pragma unroll
            for (int r = 0; r < 4; r++) {
                int row = row0 + wr * 64 + i * 16 + fq * 4 + r;
                if (row >= N) continue;
                if (col < 600) {
                    float x = fmaxf(acc[i][j][r] + bias, 0.f);
                    Hf[frag_off(row, col)] = bf16_rne(x);
                } else if (col < KP) {
                    Hf[frag_off(row, col)] = 0;
                }
            }
        }
    }
}

// GEMM2: energy += sum_col relu(H @ W2^T + b2) * W3. grid Mb*3.
__global__ __launch_bounds__(256, 4) void k_gemm2r(
        const short8* __restrict__ Af, const short8* __restrict__ Wf,
        const float* __restrict__ b2, const float* __restrict__ W3,
        float* __restrict__ energy, int N) {
    __shared__ float sE[128];
    int rowblk, colblk;
    decode_wg(3, rowblk, colblk);
    int row0 = rowblk * 128;
    int col0 = colblk * 128;
    int t = threadIdx.x, w = t >> 6, l = t & 63;
    int wr = w >> 1, wc = w & 1, fr = l & 15, fq = l >> 4;

    int aBase = (rowblk * 8 + wr * 4) * 1216 + l;
    int bBase = (colblk * 8 + wc * 4) * 1216 + l;
    f32x4 acc[4][4];
#pragma unroll
    for (int i = 0; i < 4; i++)
#pragma unroll
        for (int j = 0; j < 4; j++) acc[i][j] = f32x4{0.f, 0.f, 0.f, 0.f};
    gemm_core_reg(Af, Wf, aBase, bBase, acc);

    if (t < 128) sE[t] = 0.f;
    __syncthreads();
#pragma unroll
    for (int i = 0; i < 4; i++) {
        float p[4] = {0.f, 0.f, 0.f, 0.f};
#pragma unroll
        for (int j = 0; j < 4; j++) {
            int col = col0 + wc * 64 + j * 16 + fr;
            if (col < 300) {
                float bias = b2[col];
                float wv   = W3[col];
#pragma unroll
                for (int r = 0; r < 4; r++)
                    p[r] += fmaxf(acc[i][j][r] + bias, 0.f) * wv;
            }
        }
#pragma unroll
        for (int r = 0; r < 4; r++) {
            float v = p[r];
            v += __shfl_xor(v, 1, 64);
            v += __shfl_xor(v, 2, 64);
            v += __shfl_xor(v, 4, 64);
            v += __shfl_xor(v, 8, 64);
            p[r] = v;
        }
        if (fr == 0) {
#pragma unroll
            for (int r = 0; r < 4; r++)
                atomicAdd(&sE[wr * 64 + i * 16 + fq * 4 + r], p[r]);
        }
    }
    __syncthreads();
    if (t < 128) {
        int row = row0 + t;
        if (row < N) atomicAdd(&energy[row], sE[t]);
    }
}

// ---------------------------------------------------------------------------
// K5: per-graph pool. batch sorted -> wave-segmented reduce, few atomics.
// ---------------------------------------------------------------------------
__global__ void k_pool(const float* __restrict__ energy, const int* __restrict__ batch,
                       float* __restrict__ dg, int N) {
    int i = blockIdx.x * blockDim.x + threadIdx.x;
    int lane = threadIdx.x & 63;
    float v = (i < N) ? energy[i] : 0.f;
    int   b = (i < N) ? batch[i]  : -1;
#pragma unroll
    for (int off = 1; off < 64; off <<= 1) {
        float vv = __shfl_down(v, off, 64);
        int   bb = __shfl_down(b, off, 64);
        if (lane + off < 64 && bb == b) v += vv;
    }
    int pb = __shfl_up(b, 1, 64);
    if (i < N && (lane == 0 || pb != b)) atomicAdd(&dg[b], v);
}

extern "C" void kernel_launch(void* const* d_in, const int* in_sizes, int n_in,
                              void* d_out, int out_size, void* d_ws, size_t ws_size,
                              hipStream_t stream) {
    const int* atom       = (const int*)d_in[0];
    const int* bond_index = (const int*)d_in[1];
    const int* bond_attr  = (const int*)d_in[2];
    const int* batch      = (const int*)d_in[3];
    const float* Wa   = (const float*)d_in[4];
    const float* Wh   = (const float*)d_in[5];
    const float* War  = (const float*)d_in[6];
    const float* Wc   = (const float*)d_in[7];
    const float* Wch  = (const float*)d_in[8];
    const float* Wbt  = (const float*)d_in[9];
    const float* Wbai = (const float*)d_in[10];
    const float* Wsla = (const float*)d_in[11];
    const float* Wsl  = (const float*)d_in[12];
    const float* W1   = (const float*)d_in[13];
    const float* b1   = (const float*)d_in[14];
    const float* W2   = (const float*)d_in[15];
    const float* b2   = (const float*)d_in[16];
    const float* W3   = (const float*)d_in[17];

    int N = in_sizes[0] / 5;   // 50000
    int E = in_sizes[1] / 2;   // 100000
    int Mb = (N + 127) / 128;  // 391
    int Npad = Mb * 128;       // 50048
    int nTiles = Npad / 16;    // 3128 row-blocks
    int nb = (N + 255) / 256;  // 196 scan blocks

    size_t regionBytes = (size_t)Npad * KP * 4;
    char* base = (char*)d_ws;
    float* nodeA = (float*)base;                       // region0: embed out (fp32)
    ushortT* nodeBh = (ushortT*)(base + regionBytes);  // region1: mp1 out (bf16 rows)
    short8* Af = (short8*)nodeA;                       // region0 reuse: mp2 out frags
    short8* Hf = (short8*)nodeBh;                      // region1 reuse: gemm1 out frags
    char* tail = base + 2 * regionBytes;
    float* energy  = (float*)tail;
    int* counts    = (int*)(energy + N);
    int* offsets   = counts + N;
    int* cursor    = offsets + N;
    int* edge_list = cursor + N;
    short8* W1f    = (short8*)(edge_list + E);         // 40*19*64 tiles
    short8* W2f    = W1f + 40 * 19 * 64;               // 24*19*64 tiles
    int* blocksums = (int*)(W2f + 24 * 19 * 64);
    int* blockpref = blocksums + 256;

    const int* bsrc = bond_index;
    const int* bdst = bond_index + E;

    // CSR build (dst -> edges)
    hipMemsetAsync(counts, 0, (size_t)N * sizeof(int), stream);
    k_hist<<<(E + 255) / 256, 256, 0, stream>>>(bdst, counts, E);
    k_scan_l1<<<nb, 256, 0, stream>>>(counts, offsets, blocksums, N);
    k_scan_l2<<<1, 256, 0, stream>>>(blocksums, blockpref, nb);
    k_scan_l3<<<nb, 256, 0, stream>>>(offsets, cursor, blockpref, N);
    k_scatter<<<(E + 255) / 256, 256, 0, stream>>>(bdst, cursor, edge_list, E);

    // weight splits to fragment-interleaved single bf16
    k_split_w_frag<<<(40 * 19 * 64 + 255) / 256, 256, 0, stream>>>(W1, W1f, 600, 40);
    k_split_w_frag<<<(24 * 19 * 64 + 255) / 256, 256, 0, stream>>>(W2, W2f, 300, 24);

    // K1: node embedding -> nodeA (fp32)
    {
        int total = N * Q4;
        k_node_embed<<<(total + 255) / 256, 256, 0, stream>>>(
            atom, (const float4*)Wa, (const float4*)Wh, (const float4*)War,
            (const float4*)Wc, (const float4*)Wch, (float4*)nodeA, N);
    }

    int mpblocks = (2 * N * 64 + 255) / 256;   // two waves per node
    // round 1: nodeA (fp32) -> nodeBh (bf16 rows)
    k_mp_gather_b<<<mpblocks, 256, 0, stream>>>(bsrc, bond_attr, atom,
        offsets, counts, edge_list,
        (const float4*)Wbt, (const float4*)Wbai, (const float4*)Wsla, (const float4*)Wsl,
        (const float4*)nodeA, nodeBh, N);

    // zero A-frag pad tiles (rows N..Npad; region0 fp32 is dead now)
    {
        int firstPad = N / 16;
        size_t offB  = (size_t)firstPad * 1216 * 16;
        size_t cntB  = (size_t)(nTiles - firstPad) * 1216 * 16;
        if (cntB) hipMemsetAsync((char*)Af + offB, 0, cntB, stream);
    }

    // round 2 fused with relu + single-bf16 frag cast: nodeBh -> Af
    k_mp_gather_rs<<<mpblocks, 256, 0, stream>>>(bsrc, bond_attr, atom,
        offsets, counts, edge_list,
        (const float4*)Wbt, (const float4*)Wbai, (const float4*)Wsla, (const float4*)Wsl,
        nodeBh, (ushortT*)Af, N);

    // GEMM1: Af x W1f -> Hf (region1; nodeBh dead)
    k_gemm1r<<<Mb * 5, 256, 0, stream>>>(Af, W1f, b1, (ushortT*)Hf, N);

    // GEMM2: Hf x W2f (+b2, W3) -> energy (atomic accumulate)
    hipMemsetAsync(energy, 0, (size_t)N * sizeof(float), stream);
    k_gemm2r<<<Mb * 3, 256, 0, stream>>>(Hf, W2f, b2, W3, energy, N);

    // pool
    hipMemsetAsync(d_out, 0, (size_t)out_size * sizeof(float), stream);
    k_pool<<<(N + 255) / 256, 256, 0, stream>>>(energy, batch, (float*)d_out, N);
}